// Round 2
// baseline (586.941 us; speedup 1.0000x reference)
//
#include <hip/hip_runtime.h>
#include <math.h>

// Problem constants (fixed by reference)
constexpr int nB = 8;
constexpr int nC = 512;
constexpr int nH = 96;
constexpr int nW = 96;
constexpr int nP = nH * nW;        // 9216 pixels per batch
constexpr int nCQK = 64;           // q/k channels
constexpr int nS = nH + nW;        // 192 softmax width
constexpr int nO = 640;            // fused q(64)|k(64)|v(512)
constexpr int nM = nB * nP;        // 73728 total pixels

using short8  = __attribute__((ext_vector_type(8))) short;
using ushort8 = __attribute__((ext_vector_type(8))) unsigned short;
using floatx4 = __attribute__((ext_vector_type(4))) float;

__device__ inline unsigned pack_bf16(float a, float b) {
    unsigned ua = __float_as_uint(a), ub = __float_as_uint(b);
    ua = (ua + 0x7fff + ((ua >> 16) & 1)) >> 16;   // RNE
    ub = (ub + 0x7fff + ((ub >> 16) & 1)) >> 16;
    return ua | (ub << 16);
}
__device__ inline ushort f2bf(float a) {
    unsigned ua = __float_as_uint(a);
    return (ushort)((ua + 0x7fff + ((ua >> 16) & 1)) >> 16);
}
__device__ inline float bf2f(ushort u) {
    return __uint_as_float((unsigned)u << 16);
}

// async global->LDS, 16B per lane. LDS dest = wave-uniform base + lane*16.
typedef __attribute__((address_space(3))) unsigned int lds_u32;
typedef __attribute__((address_space(1))) const unsigned int glb_u32;
__device__ inline void gl_lds16(const void* g, void* l) {
    __builtin_amdgcn_global_load_lds((glb_u32*)g, (lds_u32*)l, 16, 0, 0);
}

// ---------------------------------------------------------------------------
// T1: x[b][c][p] fp32  ->  xT[b*nP+p][c] bf16   (64c x 64p LDS tile)
// ---------------------------------------------------------------------------
__global__ __launch_bounds__(256) void transpose_kernel(
    const float* __restrict__ x, ushort* __restrict__ xT)
{
    __shared__ float T[64 * 65];
    const int b = blockIdx.z, p0 = blockIdx.x * 64, c0 = blockIdx.y * 64;
    const int tid = threadIdx.x;
    #pragma unroll
    for (int it = 0; it < 4; ++it) {
        int c  = it * 16 + (tid >> 4);
        int p4 = (tid & 15) * 4;
        float4 v = *(const float4*)&x[((size_t)b * nC + c0 + c) * nP + p0 + p4];
        T[c * 65 + p4 + 0] = v.x; T[c * 65 + p4 + 1] = v.y;
        T[c * 65 + p4 + 2] = v.z; T[c * 65 + p4 + 3] = v.w;
    }
    __syncthreads();
    #pragma unroll
    for (int it = 0; it < 8; ++it) {
        int idx = it * 256 + tid;
        int p = idx >> 5;              // 0..63
        int c = (idx & 31) * 2;        // even c
        unsigned u = pack_bf16(T[c * 65 + p], T[(c + 1) * 65 + p]);
        *(unsigned*)&xT[((size_t)b * nP + p0 + p) * nC + c0 + c] = u;
    }
}

// ---------------------------------------------------------------------------
// T2: weights -> bf16 Wc[640][512], bias -> bc[640]. One block per o-row.
// ---------------------------------------------------------------------------
__global__ __launch_bounds__(256) void wconv_kernel(
    const float* __restrict__ Wq, const float* __restrict__ bq,
    const float* __restrict__ Wk, const float* __restrict__ bk,
    const float* __restrict__ Wv, const float* __restrict__ bv,
    ushort* __restrict__ Wc, float* __restrict__ bc)
{
    const int o = blockIdx.x, t = threadIdx.x;
    const float *src, *bsrc; int oo;
    if (o < 64)       { src = Wq; bsrc = bq; oo = o; }
    else if (o < 128) { src = Wk; bsrc = bk; oo = o - 64; }
    else              { src = Wv; bsrc = bv; oo = o - 128; }
    float2 v = *(const float2*)&src[(size_t)oo * nC + t * 2];
    *(unsigned*)&Wc[(size_t)o * nC + t * 2] = pack_bf16(v.x, v.y);
    if (t == 0) bc[o] = bsrc[oo];
}

// ---------------------------------------------------------------------------
// G: fused QKV projection via MFMA (m97 structure: global_load_lds width=16,
// linear [128][32] LDS tiles, 2-barrier K-loop, BK=32, 4 waves 2x2).
// 1D grid, N-tile-fastest + bijective XCD swizzle for A-tile L2 reuse.
// ntile==0: qk[m][o(0..127)] fp32 ; ntile>=1: swapped operands ->
//           D[c][m] -> vW[b][c][h][w] bf16 coalesced in pixel.
// ---------------------------------------------------------------------------
__global__ __launch_bounds__(256) void mfma_proj_kernel(
    const ushort* __restrict__ xT, const ushort* __restrict__ Wc,
    const float* __restrict__ bc, float* __restrict__ qk,
    ushort* __restrict__ vW)
{
    __shared__ ushort As[128 * 32];
    __shared__ ushort Bs[128 * 32];
    const int tid = threadIdx.x;

    // grid: 2880 blocks = 576 mtiles x 5 ntiles, ntile fastest.
    // XCD swizzle: each XCD gets 360 consecutive wgids (72 disjoint mtiles).
    constexpr int NWG   = (nM / 128) * (nO / 128);   // 2880
    constexpr int CHUNK = NWG / 8;                   // 360
    const int bid = blockIdx.x;
    const int wg  = (bid & 7) * CHUNK + (bid >> 3);
    const int mtile = wg / 5, ntile = wg % 5;
    const int m0 = mtile * 128, o0 = ntile * 128;

    const int lane = tid & 63;
    const int wave = tid >> 6;

    // staging: lane covers row wave*16 + (lane>>2), 16B-seg lane&3 (+64 rows)
    const ushort* gA0 = xT + (size_t)(m0 + wave * 16 + (lane >> 2)) * nC + (lane & 3) * 8;
    const ushort* gA1 = gA0 + (size_t)64 * nC;
    const ushort* gB0 = Wc + (size_t)(o0 + wave * 16 + (lane >> 2)) * nC + (lane & 3) * 8;
    const ushort* gB1 = gB0 + (size_t)64 * nC;
    ushort* lA0 = &As[wave * 16 * 32];
    ushort* lA1 = &As[(wave * 16 + 64) * 32];
    ushort* lB0 = &Bs[wave * 16 * 32];
    ushort* lB1 = &Bs[(wave * 16 + 64) * 32];

    const int wr = wave & 1, wcl = wave >> 1;
    const int lm = lane & 15, q = lane >> 4;
    int aoff[4], boff[4];
    #pragma unroll
    for (int i = 0; i < 4; ++i) aoff[i] = (wr * 64 + i * 16 + lm) * 32 + q * 8;
    #pragma unroll
    for (int j = 0; j < 4; ++j) boff[j] = (wcl * 64 + j * 16 + lm) * 32 + q * 8;

    floatx4 acc[4][4];
    #pragma unroll
    for (int i = 0; i < 4; ++i)
        #pragma unroll
        for (int j = 0; j < 4; ++j) acc[i][j] = (floatx4){0.f, 0.f, 0.f, 0.f};

    const bool vmode = (ntile != 0);

    for (int k0 = 0; k0 < nC; k0 += 32) {
        if (k0) __syncthreads();           // all waves done reading prev tile
        gl_lds16(gA0 + k0, lA0);
        gl_lds16(gA1 + k0, lA1);
        gl_lds16(gB0 + k0, lB0);
        gl_lds16(gB1 + k0, lB1);
        __syncthreads();                   // drains vmcnt -> LDS tile ready
        short8 av[4], bvv[4];
        #pragma unroll
        for (int i = 0; i < 4; ++i) av[i] = *(const short8*)&As[aoff[i]];
        #pragma unroll
        for (int j = 0; j < 4; ++j) bvv[j] = *(const short8*)&Bs[boff[j]];
        if (!vmode) {
            #pragma unroll
            for (int i = 0; i < 4; ++i)
                #pragma unroll
                for (int j = 0; j < 4; ++j)
                    acc[i][j] = __builtin_amdgcn_mfma_f32_16x16x32_bf16(
                        av[i], bvv[j], acc[i][j], 0, 0, 0);
        } else {
            // swapped: D rows = Wc-row (o/c), D cols = xT-row (m)
            #pragma unroll
            for (int i = 0; i < 4; ++i)
                #pragma unroll
                for (int j = 0; j < 4; ++j)
                    acc[i][j] = __builtin_amdgcn_mfma_f32_16x16x32_bf16(
                        bvv[i], av[j], acc[i][j], 0, 0, 0);
        }
    }

    if (!vmode) {
        // D: col(lm)=o, row(q*4+r)=m
        float bj[4];
        #pragma unroll
        for (int j = 0; j < 4; ++j) bj[j] = bc[wcl * 64 + j * 16 + lm];
        #pragma unroll
        for (int i = 0; i < 4; ++i) {
            #pragma unroll
            for (int r = 0; r < 4; ++r) {
                int mrow = m0 + wr * 64 + i * 16 + q * 4 + r;
                float* orow = qk + (size_t)mrow * 128 + wcl * 64 + lm;
                #pragma unroll
                for (int j = 0; j < 4; ++j) orow[j * 16] = acc[i][j][r] + bj[j];
            }
        }
    } else {
        // D: row(q*4+r)=o (c), col(lm)=m (pixel)
        const int b  = m0 / nP;
        const int p0 = m0 - b * nP;
        #pragma unroll
        for (int i = 0; i < 4; ++i) {
            #pragma unroll
            for (int r = 0; r < 4; ++r) {
                int o = o0 + wcl * 64 + i * 16 + q * 4 + r;
                float bias = bc[o];
                int c = o - 128;
                ushort* vrow = vW + ((size_t)(b * nC + c)) * nP + p0 + wr * 64 + lm;
                #pragma unroll
                for (int j = 0; j < 4; ++j)
                    vrow[j * 16] = f2bf(acc[i][j][r] + bias);
            }
        }
    }
}

// ---------------------------------------------------------------------------
// vtrans: vW[b][c][h][w] -> vH[b][c][w][h]  (bf16 96x96 spatial transpose)
// XOR-swizzled 16-chunk rows so the column gather is bank-conflict-free.
// ---------------------------------------------------------------------------
__global__ __launch_bounds__(256) void vtrans_kernel(
    const ushort* __restrict__ vW, ushort* __restrict__ vH)
{
    __shared__ ushort T[96 * 128];
    const int c = blockIdx.x, b = blockIdx.y, tid = threadIdx.x;
    const size_t base = ((size_t)(b * nC + c)) * nP;
    for (int l = tid; l < 96 * 12; l += 256) {
        int hh = l / 12, seg = l % 12;
        uint4 u = *(const uint4*)&vW[base + (size_t)hh * nW + seg * 8];
        *(uint4*)&T[hh * 128 + ((seg ^ ((hh >> 3) & 7)) * 8)] = u;
    }
    __syncthreads();
    for (int l = tid; l < 96 * 12; l += 256) {
        int ww = l / 12, seg = l % 12;
        ushort8 vv;
        #pragma unroll
        for (int e = 0; e < 8; ++e) {
            int hh = seg * 8 + e;
            int phys = (((ww >> 3) ^ ((hh >> 3) & 7)) * 8) + (ww & 7);
            vv[e] = T[hh * 128 + phys];
        }
        *(ushort8*)&vH[base + (size_t)ww * nH + seg * 8] = vv;
    }
}

// ---------------------------------------------------------------------------
// scores: mode 0 (H): per (b,w) -> eH[h][g], diag=-inf ; mode 1 (W): per (b,h)
// q/k read from qk[m][128] fp32 (offsets 0 / 64).
// ---------------------------------------------------------------------------
__global__ __launch_bounds__(256) void score_kernel(
    const float* __restrict__ qk, float* __restrict__ att, int mode)
{
    __shared__ float Qs[96][68];
    __shared__ float Ks[96][68];
    const int b   = blockIdx.y;
    const int fix = blockIdx.x;
    const int tid = threadIdx.x;

    for (int l = tid; l < 96 * 16; l += 256) {
        int r  = l / 16;
        int c4 = (l % 16) * 4;
        size_t p = (mode == 0) ? ((size_t)r * nW + fix) : ((size_t)fix * nW + r);
        const float* row = &qk[((size_t)b * nP + p) * 128];
        *(float4*)&Qs[r][c4] = *(const float4*)&row[c4];
        *(float4*)&Ks[r][c4] = *(const float4*)&row[64 + c4];
    }
    __syncthreads();

    const int tx = tid % 16;
    const int ty = tid / 16;
    float acc[6][6] = {};
    for (int c4 = 0; c4 < nCQK; c4 += 4) {
        float4 qv[6], kv[6];
        #pragma unroll
        for (int i = 0; i < 6; ++i) qv[i] = *(const float4*)&Qs[ty + 16 * i][c4];
        #pragma unroll
        for (int j = 0; j < 6; ++j) kv[j] = *(const float4*)&Ks[tx + 16 * j][c4];
        #pragma unroll
        for (int i = 0; i < 6; ++i)
            #pragma unroll
            for (int j = 0; j < 6; ++j)
                acc[i][j] += qv[i].x * kv[j].x + qv[i].y * kv[j].y
                           + qv[i].z * kv[j].z + qv[i].w * kv[j].w;
    }

    #pragma unroll
    for (int i = 0; i < 6; ++i) {
        int row = ty + 16 * i;
        #pragma unroll
        for (int j = 0; j < 6; ++j) {
            int col = tx + 16 * j;
            float val = acc[i][j];
            if (mode == 0) {
                if (col == row) val = -INFINITY;
                att[((size_t)b * nP + row * nW + fix) * nS + col] = val;
            } else {
                att[((size_t)b * nP + fix * nW + row) * nS + 96 + col] = val;
            }
        }
    }
}

// ---------------------------------------------------------------------------
// softmax over 192 entries per pixel; fp32 in, bf16 out. One wave per pixel.
// ---------------------------------------------------------------------------
__global__ __launch_bounds__(256) void softmax_kernel(
    const float* __restrict__ att, ushort* __restrict__ attb)
{
    const int wav  = threadIdx.x / 64;
    const int lane = threadIdx.x % 64;
    const size_t pix = (size_t)blockIdx.x * 4 + wav;
    const float* a = att + pix * nS;
    ushort* ab = attb + pix * nS;
    float v0 = a[lane], v1 = a[lane + 64], v2 = a[lane + 128];
    float m = fmaxf(fmaxf(v0, v1), v2);
    #pragma unroll
    for (int off = 32; off; off >>= 1) m = fmaxf(m, __shfl_xor(m, off));
    float e0 = __expf(v0 - m), e1 = __expf(v1 - m), e2 = __expf(v2 - m);
    float s = e0 + e1 + e2;
    #pragma unroll
    for (int off = 32; off; off >>= 1) s += __shfl_xor(s, off);
    float inv = 1.0f / s;
    ab[lane]       = f2bf(e0 * inv);
    ab[lane + 64]  = f2bf(e1 * inv);
    ab[lane + 128] = f2bf(e2 * inv);
}

// ---------------------------------------------------------------------------
// aggH (MFMA): per (b,w): OH[h][c] = sum_g AH[h][g] * vH[c][g]
//   A = attb rows (H half, g-contig); B = vH rows (g-contig).
//   D rows=h, cols=c -> oh[b,p(h,w)][c] bf16, c-coalesced stores.
// ---------------------------------------------------------------------------
__global__ __launch_bounds__(256) void aggH_kernel(
    const ushort* __restrict__ attb, const ushort* __restrict__ vH,
    ushort* __restrict__ oh)
{
    __shared__ ushort As[96 * 104];    // AH[h][g]
    __shared__ ushort Bs[128 * 104];   // vH c-tile [c][g]
    const int b = blockIdx.y, w = blockIdx.x, tid = threadIdx.x;

    for (int l = tid; l < 96 * 12; l += 256) {
        int h = l / 12, seg = l % 12;
        uint4 u = *(const uint4*)&attb[((size_t)(b * nP + h * nW + w)) * nS + seg * 8];
        *(uint4*)&As[h * 104 + seg * 8] = u;
    }
    const int lane = tid & 63, wave = tid >> 6;
    const int wr = wave & 1, wc = wave >> 1;
    const int lm = lane & 15, q = lane >> 4;
    int aoff[3], boff[4];
    #pragma unroll
    for (int i = 0; i < 3; ++i) aoff[i] = (wr * 48 + i * 16 + lm) * 104 + q * 8;
    #pragma unroll
    for (int j = 0; j < 4; ++j) boff[j] = (wc * 64 + j * 16 + lm) * 104 + q * 8;

    for (int ct = 0; ct < 4; ++ct) {
        if (ct) __syncthreads();
        for (int l = tid; l < 128 * 12; l += 256) {
            int cl = l / 12, seg = l % 12;
            uint4 u = *(const uint4*)&vH[((size_t)(b * nC + ct * 128 + cl)) * nP
                                         + w * nH + seg * 8];
            *(uint4*)&Bs[cl * 104 + seg * 8] = u;
        }
        __syncthreads();
        floatx4 acc[3][4];
        #pragma unroll
        for (int i = 0; i < 3; ++i)
            #pragma unroll
            for (int j = 0; j < 4; ++j) acc[i][j] = (floatx4){0.f, 0.f, 0.f, 0.f};
        #pragma unroll
        for (int ks = 0; ks < 3; ++ks) {
            short8 av[3], bvv[4];
            #pragma unroll
            for (int i = 0; i < 3; ++i) av[i] = *(const short8*)&As[aoff[i] + ks * 32];
            #pragma unroll
            for (int j = 0; j < 4; ++j) bvv[j] = *(const short8*)&Bs[boff[j] + ks * 32];
            #pragma unroll
            for (int i = 0; i < 3; ++i)
                #pragma unroll
                for (int j = 0; j < 4; ++j)
                    acc[i][j] = __builtin_amdgcn_mfma_f32_16x16x32_bf16(
                        av[i], bvv[j], acc[i][j], 0, 0, 0);
        }
        #pragma unroll
        for (int i = 0; i < 3; ++i) {
            #pragma unroll
            for (int r = 0; r < 4; ++r) {
                int h = wr * 48 + i * 16 + q * 4 + r;
                ushort* orow = oh + ((size_t)(b * nP + h * nW + w)) * nC
                               + ct * 128 + wc * 64 + lm;
                #pragma unroll
                for (int j = 0; j < 4; ++j) orow[j * 16] = f2bf(acc[i][j][r]);
            }
        }
    }
}

// ---------------------------------------------------------------------------
// aggW (MFMA) + epilogue: per (b,h): OW[w][c] = sum_u AW[w][u] * vW[c][u]
//   swapped operands -> D rows=c, cols=w; out NCHW is w-coalesced.
//   oh tile staged via LDS (layout bridge [p][c] -> [c][w]).
//   out = gamma*(OW + OH) + x.
// ---------------------------------------------------------------------------
__global__ __launch_bounds__(256) void aggW_kernel(
    const ushort* __restrict__ attb, const ushort* __restrict__ vW,
    const ushort* __restrict__ oh, const float* __restrict__ x,
    const float* __restrict__ gamma, float* __restrict__ out)
{
    __shared__ ushort As[96 * 104];    // AW[w][u]
    __shared__ ushort Bs[64 * 104];    // vW c-tile [c][u]
    __shared__ ushort Os[96 * 72];     // oh tile [w][cl]
    const int b = blockIdx.y, h = blockIdx.x, tid = threadIdx.x;
    const float gm = gamma[0];

    for (int l = tid; l < 96 * 12; l += 256) {
        int ww = l / 12, seg = l % 12;
        uint4 u = *(const uint4*)&attb[((size_t)(b * nP + h * nW + ww)) * nS
                                       + 96 + seg * 8];
        *(uint4*)&As[ww * 104 + seg * 8] = u;
    }
    const int lane = tid & 63, wave = tid >> 6;
    const int wr = wave & 1, wc = wave >> 1;   // wr: w-half, wc: c-half
    const int lm = lane & 15, q = lane >> 4;
    int coff[2], woff[3];
    #pragma unroll
    for (int i = 0; i < 2; ++i) coff[i] = (wc * 32 + i * 16 + lm) * 104 + q * 8;
    #pragma unroll
    for (int j = 0; j < 3; ++j) woff[j] = (wr * 48 + j * 16 + lm) * 104 + q * 8;

    for (int ct = 0; ct < 8; ++ct) {
        if (ct) __syncthreads();
        for (int l = tid; l < 64 * 12; l += 256) {
            int cl = l / 12, seg = l % 12;
            uint4 u = *(const uint4*)&vW[((size_t)(b * nC + ct * 64 + cl)) * nP
                                         + h * nW + seg * 8];
            *(uint4*)&Bs[cl * 104 + seg * 8] = u;
        }
        for (int l = tid; l < 96 * 8; l += 256) {
            int ww = l / 8, seg = l % 8;
            uint4 u = *(const uint4*)&oh[((size_t)(b * nP + h * nW + ww)) * nC
                                         + ct * 64 + seg * 8];
            *(uint4*)&Os[ww * 72 + seg * 8] = u;
        }
        __syncthreads();
        floatx4 acc[2][3];
        #pragma unroll
        for (int i = 0; i < 2; ++i)
            #pragma unroll
            for (int j = 0; j < 3; ++j) acc[i][j] = (floatx4){0.f, 0.f, 0.f, 0.f};
        #pragma unroll
        for (int ks = 0; ks < 3; ++ks) {
            short8 cv[2], wv[3];
            #pragma unroll
            for (int i = 0; i < 2; ++i) cv[i] = *(const short8*)&Bs[coff[i] + ks * 32];
            #pragma unroll
            for (int j = 0; j < 3; ++j) wv[j] = *(const short8*)&As[woff[j] + ks * 32];
            #pragma unroll
            for (int i = 0; i < 2; ++i)
                #pragma unroll
                for (int j = 0; j < 3; ++j)
                    acc[i][j] = __builtin_amdgcn_mfma_f32_16x16x32_bf16(
                        cv[i], wv[j], acc[i][j], 0, 0, 0);
        }
        // D: row(q*4+r)=c, col(lm)=w
        #pragma unroll
        for (int i = 0; i < 2; ++i) {
            #pragma unroll
            for (int r = 0; r < 4; ++r) {
                int cl = wc * 32 + i * 16 + q * 4 + r;
                int c  = ct * 64 + cl;
                #pragma unroll
                for (int j = 0; j < 3; ++j) {
                    int ww = wr * 48 + j * 16 + lm;
                    size_t oidx = ((size_t)(b * nC + c) * nH + h) * nW + ww;
                    float ohv = bf2f(Os[ww * 72 + cl]);
                    out[oidx] = gm * (acc[i][j][r] + ohv) + x[oidx];
                }
            }
        }
    }
}

// ---------------------------------------------------------------------------
extern "C" void kernel_launch(void* const* d_in, const int* in_sizes, int n_in,
                              void* d_out, int out_size, void* d_ws, size_t ws_size,
                              hipStream_t stream)
{
    const float* x     = (const float*)d_in[0];
    const float* Wq    = (const float*)d_in[1];
    const float* bq    = (const float*)d_in[2];
    const float* Wk    = (const float*)d_in[3];
    const float* bk    = (const float*)d_in[4];
    const float* Wv    = (const float*)d_in[5];
    const float* bv    = (const float*)d_in[6];
    const float* gamma = (const float*)d_in[7];
    float* out = (float*)d_out;

    // Workspace layout (349.2 MB):
    //  R1 [nM*nC bf16 = 75.5MB]: xT until proj done, then vH (vtrans output)
    //  R2 [nM*128 f32 = 37.7MB]: qk
    //  R3 [nM*nC bf16 = 75.5MB]: vW
    //  R4 [nM*nS f32  = 56.6MB]: Wc+bc (bf16 weights) until scores, then att
    //  R5 [nM*nS bf16 = 28.3MB]: attb
    //  R6 [nM*nC bf16 = 75.5MB]: oh
    char* p = (char*)d_ws;
    ushort* xT  = (ushort*)p;
    ushort* vH  = (ushort*)p;
    p += (size_t)nM * nC * 2;
    float* qk   = (float*)p;
    p += (size_t)nM * 128 * 4;
    ushort* vW  = (ushort*)p;
    p += (size_t)nM * nC * 2;
    float* att  = (float*)p;
    ushort* Wc  = (ushort*)p;
    float* bc   = (float*)(p + (size_t)nO * nC * 2);
    p += (size_t)nM * nS * 4;
    ushort* attb = (ushort*)p;
    p += (size_t)nM * nS * 2;
    ushort* oh  = (ushort*)p;

    dim3 blk(256);
    transpose_kernel<<<dim3(nP / 64, nC / 64, nB), blk, 0, stream>>>(x, xT);
    wconv_kernel<<<dim3(nO), blk, 0, stream>>>(Wq, bq, Wk, bk, Wv, bv, Wc, bc);
    mfma_proj_kernel<<<dim3((nM / 128) * (nO / 128)), blk, 0, stream>>>(xT, Wc, bc, qk, vW);
    vtrans_kernel<<<dim3(nC, nB), blk, 0, stream>>>(vW, vH);
    score_kernel<<<dim3(nW, nB), blk, 0, stream>>>(qk, att, 0);
    score_kernel<<<dim3(nH, nB), blk, 0, stream>>>(qk, att, 1);
    softmax_kernel<<<dim3(nB * nP / 4), blk, 0, stream>>>(att, attb);
    aggH_kernel<<<dim3(nW, nB), blk, 0, stream>>>(attb, vH, oh);
    aggW_kernel<<<dim3(nH, nB), blk, 0, stream>>>(attb, vW, oh, x, gamma, out);
}

// Round 3
// 576.301 us; speedup vs baseline: 1.0185x; 1.0185x over previous
//
#include <hip/hip_runtime.h>
#include <math.h>

// Problem constants (fixed by reference)
constexpr int nB = 8;
constexpr int nC = 512;
constexpr int nH = 96;
constexpr int nW = 96;
constexpr int nP = nH * nW;        // 9216 pixels per batch
constexpr int nCQK = 64;           // q/k channels
constexpr int nS = nH + nW;        // 192 softmax width
constexpr int nO = 640;            // fused q(64)|k(64)|v(512)
constexpr int nM = nB * nP;        // 73728 total pixels

using short8  = __attribute__((ext_vector_type(8))) short;
using ushort8 = __attribute__((ext_vector_type(8))) unsigned short;
using floatx4 = __attribute__((ext_vector_type(4))) float;

__device__ inline unsigned pack_bf16(float a, float b) {
    unsigned ua = __float_as_uint(a), ub = __float_as_uint(b);
    ua = (ua + 0x7fff + ((ua >> 16) & 1)) >> 16;   // RNE
    ub = (ub + 0x7fff + ((ub >> 16) & 1)) >> 16;
    return ua | (ub << 16);
}
__device__ inline ushort f2bf(float a) {
    unsigned ua = __float_as_uint(a);
    return (ushort)((ua + 0x7fff + ((ua >> 16) & 1)) >> 16);
}
__device__ inline float bf2f(ushort u) {
    return __uint_as_float((unsigned)u << 16);
}

// async global->LDS, 16B per lane. LDS dest = wave-uniform base + lane*16.
typedef __attribute__((address_space(3))) unsigned int lds_u32;
typedef __attribute__((address_space(1))) const unsigned int glb_u32;
__device__ inline void gl_lds16(const void* g, void* l) {
    __builtin_amdgcn_global_load_lds((glb_u32*)g, (lds_u32*)l, 16, 0, 0);
}

// ---------------------------------------------------------------------------
// T1: x[b][c][p] fp32  ->  xT[b*nP+p][c] bf16   (64c x 64p LDS tile)
// ---------------------------------------------------------------------------
__global__ __launch_bounds__(256) void transpose_kernel(
    const float* __restrict__ x, ushort* __restrict__ xT)
{
    __shared__ float T[64 * 65];
    const int b = blockIdx.z, p0 = blockIdx.x * 64, c0 = blockIdx.y * 64;
    const int tid = threadIdx.x;
    #pragma unroll
    for (int it = 0; it < 4; ++it) {
        int c  = it * 16 + (tid >> 4);
        int p4 = (tid & 15) * 4;
        float4 v = *(const float4*)&x[((size_t)b * nC + c0 + c) * nP + p0 + p4];
        T[c * 65 + p4 + 0] = v.x; T[c * 65 + p4 + 1] = v.y;
        T[c * 65 + p4 + 2] = v.z; T[c * 65 + p4 + 3] = v.w;
    }
    __syncthreads();
    #pragma unroll
    for (int it = 0; it < 8; ++it) {
        int idx = it * 256 + tid;
        int p = idx >> 5;              // 0..63
        int c = (idx & 31) * 2;        // even c
        unsigned u = pack_bf16(T[c * 65 + p], T[(c + 1) * 65 + p]);
        *(unsigned*)&xT[((size_t)b * nP + p0 + p) * nC + c0 + c] = u;
    }
}

// ---------------------------------------------------------------------------
// T2: weights -> bf16 Wc[640][512], bias -> bc[640]. One block per o-row.
// ---------------------------------------------------------------------------
__global__ __launch_bounds__(256) void wconv_kernel(
    const float* __restrict__ Wq, const float* __restrict__ bq,
    const float* __restrict__ Wk, const float* __restrict__ bk,
    const float* __restrict__ Wv, const float* __restrict__ bv,
    ushort* __restrict__ Wc, float* __restrict__ bc)
{
    const int o = blockIdx.x, t = threadIdx.x;
    const float *src, *bsrc; int oo;
    if (o < 64)       { src = Wq; bsrc = bq; oo = o; }
    else if (o < 128) { src = Wk; bsrc = bk; oo = o - 64; }
    else              { src = Wv; bsrc = bv; oo = o - 128; }
    float2 v = *(const float2*)&src[(size_t)oo * nC + t * 2];
    *(unsigned*)&Wc[(size_t)o * nC + t * 2] = pack_bf16(v.x, v.y);
    if (t == 0) bc[o] = bsrc[oo];
}

// ---------------------------------------------------------------------------
// G: fused QKV projection via MFMA.
// T3 minimum 2-phase double-buffer: stage tile t+1 (global_load_lds w=16,
// linear [128][32] LDS) BEFORE ds_read+MFMA of tile t; ONE vmcnt-drain
// barrier per K-step -> load latency hides under the 16-MFMA phase.
// 1D grid, N-tile-fastest + XCD swizzle (keeps FETCH at ~46 MB, L3-resident).
// ntile==0: qk[m][o(0..127)] fp32 ; ntile>=1: swapped operands ->
//           D[c][m] -> vW[b][c][h][w] bf16 coalesced in pixel.
// ---------------------------------------------------------------------------
__global__ __launch_bounds__(256) void mfma_proj_kernel(
    const ushort* __restrict__ xT, const ushort* __restrict__ Wc,
    const float* __restrict__ bc, float* __restrict__ qk,
    ushort* __restrict__ vW)
{
    __shared__ ushort As[2][128 * 32];
    __shared__ ushort Bs[2][128 * 32];
    const int tid = threadIdx.x;

    // grid: 2880 blocks = 576 mtiles x 5 ntiles, ntile fastest.
    // XCD swizzle: each XCD gets 360 consecutive wgids (72 disjoint mtiles).
    constexpr int NWG   = (nM / 128) * (nO / 128);   // 2880
    constexpr int CHUNK = NWG / 8;                   // 360
    const int bid = blockIdx.x;
    const int wg  = (bid & 7) * CHUNK + (bid >> 3);
    const int mtile = wg / 5, ntile = wg % 5;
    const int m0 = mtile * 128, o0 = ntile * 128;

    const int lane = tid & 63;
    const int wave = tid >> 6;

    // staging: lane covers row wave*16 + (lane>>2), 16B-seg lane&3 (+64 rows)
    const ushort* gA0 = xT + (size_t)(m0 + wave * 16 + (lane >> 2)) * nC + (lane & 3) * 8;
    const ushort* gA1 = gA0 + (size_t)64 * nC;
    const ushort* gB0 = Wc + (size_t)(o0 + wave * 16 + (lane >> 2)) * nC + (lane & 3) * 8;
    const ushort* gB1 = gB0 + (size_t)64 * nC;
    const int lbase  = wave * 16 * 32;          // wave-uniform LDS row base
    const int lbase1 = lbase + 64 * 32;

    const int wr = wave & 1, wcl = wave >> 1;
    const int lm = lane & 15, q = lane >> 4;
    int aoff[4], boff[4];
    #pragma unroll
    for (int i = 0; i < 4; ++i) aoff[i] = (wr * 64 + i * 16 + lm) * 32 + q * 8;
    #pragma unroll
    for (int j = 0; j < 4; ++j) boff[j] = (wcl * 64 + j * 16 + lm) * 32 + q * 8;

    floatx4 acc[4][4];
    #pragma unroll
    for (int i = 0; i < 4; ++i)
        #pragma unroll
        for (int j = 0; j < 4; ++j) acc[i][j] = (floatx4){0.f, 0.f, 0.f, 0.f};

    const bool vmode = (ntile != 0);

    // prologue: stage K-step 0 into buf 0
    gl_lds16(gA0, &As[0][lbase]);
    gl_lds16(gA1, &As[0][lbase1]);
    gl_lds16(gB0, &Bs[0][lbase]);
    gl_lds16(gB1, &Bs[0][lbase1]);
    __syncthreads();                       // drains vmcnt -> buf0 ready

    #pragma unroll 2
    for (int t = 0; t < 16; ++t) {
        const int cur = t & 1;
        if (t < 15) {                      // issue next tile EARLY
            const int k0 = (t + 1) * 32;
            gl_lds16(gA0 + k0, &As[cur ^ 1][lbase]);
            gl_lds16(gA1 + k0, &As[cur ^ 1][lbase1]);
            gl_lds16(gB0 + k0, &Bs[cur ^ 1][lbase]);
            gl_lds16(gB1 + k0, &Bs[cur ^ 1][lbase1]);
        }
        short8 av[4], bvv[4];
        #pragma unroll
        for (int i = 0; i < 4; ++i) av[i] = *(const short8*)&As[cur][aoff[i]];
        #pragma unroll
        for (int j = 0; j < 4; ++j) bvv[j] = *(const short8*)&Bs[cur][boff[j]];
        if (!vmode) {
            #pragma unroll
            for (int i = 0; i < 4; ++i)
                #pragma unroll
                for (int j = 0; j < 4; ++j)
                    acc[i][j] = __builtin_amdgcn_mfma_f32_16x16x32_bf16(
                        av[i], bvv[j], acc[i][j], 0, 0, 0);
        } else {
            // swapped: D rows = Wc-row (o/c), D cols = xT-row (m)
            #pragma unroll
            for (int i = 0; i < 4; ++i)
                #pragma unroll
                for (int j = 0; j < 4; ++j)
                    acc[i][j] = __builtin_amdgcn_mfma_f32_16x16x32_bf16(
                        bvv[i], av[j], acc[i][j], 0, 0, 0);
        }
        if (t < 15) __syncthreads();       // one drain+sync per K-step
    }

    if (!vmode) {
        // D: col(lm)=o, row(q*4+r)=m
        float bj[4];
        #pragma unroll
        for (int j = 0; j < 4; ++j) bj[j] = bc[wcl * 64 + j * 16 + lm];
        #pragma unroll
        for (int i = 0; i < 4; ++i) {
            #pragma unroll
            for (int r = 0; r < 4; ++r) {
                int mrow = m0 + wr * 64 + i * 16 + q * 4 + r;
                float* orow = qk + (size_t)mrow * 128 + wcl * 64 + lm;
                #pragma unroll
                for (int j = 0; j < 4; ++j) orow[j * 16] = acc[i][j][r] + bj[j];
            }
        }
    } else {
        // D: row(q*4+r)=o (c), col(lm)=m (pixel)
        const int b  = m0 / nP;
        const int p0 = m0 - b * nP;
        #pragma unroll
        for (int i = 0; i < 4; ++i) {
            #pragma unroll
            for (int r = 0; r < 4; ++r) {
                int o = o0 + wcl * 64 + i * 16 + q * 4 + r;
                float bias = bc[o];
                int c = o - 128;
                ushort* vrow = vW + ((size_t)(b * nC + c)) * nP + p0 + wr * 64 + lm;
                #pragma unroll
                for (int j = 0; j < 4; ++j)
                    vrow[j * 16] = f2bf(acc[i][j][r] + bias);
            }
        }
    }
}

// ---------------------------------------------------------------------------
// vtrans: vW[b][c][h][w] -> vH[b][c][w][h]  (bf16 96x96 spatial transpose)
// XOR-swizzled 16-chunk rows so the column gather is bank-conflict-free.
// ---------------------------------------------------------------------------
__global__ __launch_bounds__(256) void vtrans_kernel(
    const ushort* __restrict__ vW, ushort* __restrict__ vH)
{
    __shared__ ushort T[96 * 128];
    const int c = blockIdx.x, b = blockIdx.y, tid = threadIdx.x;
    const size_t base = ((size_t)(b * nC + c)) * nP;
    for (int l = tid; l < 96 * 12; l += 256) {
        int hh = l / 12, seg = l % 12;
        uint4 u = *(const uint4*)&vW[base + (size_t)hh * nW + seg * 8];
        *(uint4*)&T[hh * 128 + ((seg ^ ((hh >> 3) & 7)) * 8)] = u;
    }
    __syncthreads();
    for (int l = tid; l < 96 * 12; l += 256) {
        int ww = l / 12, seg = l % 12;
        ushort8 vv;
        #pragma unroll
        for (int e = 0; e < 8; ++e) {
            int hh = seg * 8 + e;
            int phys = (((ww >> 3) ^ ((hh >> 3) & 7)) * 8) + (ww & 7);
            vv[e] = T[hh * 128 + phys];
        }
        *(ushort8*)&vH[base + (size_t)ww * nH + seg * 8] = vv;
    }
}

// ---------------------------------------------------------------------------
// scores: mode 0 (H): per (b,w) -> eH[h][g], diag=-inf ; mode 1 (W): per (b,h)
// q/k read from qk[m][128] fp32 (offsets 0 / 64).
// ---------------------------------------------------------------------------
__global__ __launch_bounds__(256) void score_kernel(
    const float* __restrict__ qk, float* __restrict__ att, int mode)
{
    __shared__ float Qs[96][68];
    __shared__ float Ks[96][68];
    const int b   = blockIdx.y;
    const int fix = blockIdx.x;
    const int tid = threadIdx.x;

    for (int l = tid; l < 96 * 16; l += 256) {
        int r  = l / 16;
        int c4 = (l % 16) * 4;
        size_t p = (mode == 0) ? ((size_t)r * nW + fix) : ((size_t)fix * nW + r);
        const float* row = &qk[((size_t)b * nP + p) * 128];
        *(float4*)&Qs[r][c4] = *(const float4*)&row[c4];
        *(float4*)&Ks[r][c4] = *(const float4*)&row[64 + c4];
    }
    __syncthreads();

    const int tx = tid % 16;
    const int ty = tid / 16;
    float acc[6][6] = {};
    for (int c4 = 0; c4 < nCQK; c4 += 4) {
        float4 qv[6], kv[6];
        #pragma unroll
        for (int i = 0; i < 6; ++i) qv[i] = *(const float4*)&Qs[ty + 16 * i][c4];
        #pragma unroll
        for (int j = 0; j < 6; ++j) kv[j] = *(const float4*)&Ks[tx + 16 * j][c4];
        #pragma unroll
        for (int i = 0; i < 6; ++i)
            #pragma unroll
            for (int j = 0; j < 6; ++j)
                acc[i][j] += qv[i].x * kv[j].x + qv[i].y * kv[j].y
                           + qv[i].z * kv[j].z + qv[i].w * kv[j].w;
    }

    #pragma unroll
    for (int i = 0; i < 6; ++i) {
        int row = ty + 16 * i;
        #pragma unroll
        for (int j = 0; j < 6; ++j) {
            int col = tx + 16 * j;
            float val = acc[i][j];
            if (mode == 0) {
                if (col == row) val = -INFINITY;
                att[((size_t)b * nP + row * nW + fix) * nS + col] = val;
            } else {
                att[((size_t)b * nP + fix * nW + row) * nS + 96 + col] = val;
            }
        }
    }
}

// ---------------------------------------------------------------------------
// softmax over 192 entries per pixel; fp32 in, bf16 out. One wave per pixel.
// ---------------------------------------------------------------------------
__global__ __launch_bounds__(256) void softmax_kernel(
    const float* __restrict__ att, ushort* __restrict__ attb)
{
    const int wav  = threadIdx.x / 64;
    const int lane = threadIdx.x % 64;
    const size_t pix = (size_t)blockIdx.x * 4 + wav;
    const float* a = att + pix * nS;
    ushort* ab = attb + pix * nS;
    float v0 = a[lane], v1 = a[lane + 64], v2 = a[lane + 128];
    float m = fmaxf(fmaxf(v0, v1), v2);
    #pragma unroll
    for (int off = 32; off; off >>= 1) m = fmaxf(m, __shfl_xor(m, off));
    float e0 = __expf(v0 - m), e1 = __expf(v1 - m), e2 = __expf(v2 - m);
    float s = e0 + e1 + e2;
    #pragma unroll
    for (int off = 32; off; off >>= 1) s += __shfl_xor(s, off);
    float inv = 1.0f / s;
    ab[lane]       = f2bf(e0 * inv);
    ab[lane + 64]  = f2bf(e1 * inv);
    ab[lane + 128] = f2bf(e2 * inv);
}

// ---------------------------------------------------------------------------
// aggH (MFMA): per (b,w): OH[h][c] = sum_g AH[h][g] * vH[c][g]
//   A = attb rows (H half, g-contig); B = vH rows (g-contig).
//   D rows=h, cols=c -> oh[b,p(h,w)][c] bf16, c-coalesced stores.
// ---------------------------------------------------------------------------
__global__ __launch_bounds__(256) void aggH_kernel(
    const ushort* __restrict__ attb, const ushort* __restrict__ vH,
    ushort* __restrict__ oh)
{
    __shared__ ushort As[96 * 104];    // AH[h][g]
    __shared__ ushort Bs[128 * 104];   // vH c-tile [c][g]
    const int b = blockIdx.y, w = blockIdx.x, tid = threadIdx.x;

    for (int l = tid; l < 96 * 12; l += 256) {
        int h = l / 12, seg = l % 12;
        uint4 u = *(const uint4*)&attb[((size_t)(b * nP + h * nW + w)) * nS + seg * 8];
        *(uint4*)&As[h * 104 + seg * 8] = u;
    }
    const int lane = tid & 63, wave = tid >> 6;
    const int wr = wave & 1, wc = wave >> 1;
    const int lm = lane & 15, q = lane >> 4;
    int aoff[3], boff[4];
    #pragma unroll
    for (int i = 0; i < 3; ++i) aoff[i] = (wr * 48 + i * 16 + lm) * 104 + q * 8;
    #pragma unroll
    for (int j = 0; j < 4; ++j) boff[j] = (wc * 64 + j * 16 + lm) * 104 + q * 8;

    for (int ct = 0; ct < 4; ++ct) {
        if (ct) __syncthreads();
        for (int l = tid; l < 128 * 12; l += 256) {
            int cl = l / 12, seg = l % 12;
            uint4 u = *(const uint4*)&vH[((size_t)(b * nC + ct * 128 + cl)) * nP
                                         + w * nH + seg * 8];
            *(uint4*)&Bs[cl * 104 + seg * 8] = u;
        }
        __syncthreads();
        floatx4 acc[3][4];
        #pragma unroll
        for (int i = 0; i < 3; ++i)
            #pragma unroll
            for (int j = 0; j < 4; ++j) acc[i][j] = (floatx4){0.f, 0.f, 0.f, 0.f};
        #pragma unroll
        for (int ks = 0; ks < 3; ++ks) {
            short8 av[3], bvv[4];
            #pragma unroll
            for (int i = 0; i < 3; ++i) av[i] = *(const short8*)&As[aoff[i] + ks * 32];
            #pragma unroll
            for (int j = 0; j < 4; ++j) bvv[j] = *(const short8*)&Bs[boff[j] + ks * 32];
            #pragma unroll
            for (int i = 0; i < 3; ++i)
                #pragma unroll
                for (int j = 0; j < 4; ++j)
                    acc[i][j] = __builtin_amdgcn_mfma_f32_16x16x32_bf16(
                        av[i], bvv[j], acc[i][j], 0, 0, 0);
        }
        #pragma unroll
        for (int i = 0; i < 3; ++i) {
            #pragma unroll
            for (int r = 0; r < 4; ++r) {
                int h = wr * 48 + i * 16 + q * 4 + r;
                ushort* orow = oh + ((size_t)(b * nP + h * nW + w)) * nC
                               + ct * 128 + wc * 64 + lm;
                #pragma unroll
                for (int j = 0; j < 4; ++j) orow[j * 16] = f2bf(acc[i][j][r]);
            }
        }
    }
}

// ---------------------------------------------------------------------------
// aggW (MFMA) + epilogue: per (b,h): OW[w][c] = sum_u AW[w][u] * vW[c][u]
//   swapped operands -> D rows=c, cols=w; out NCHW is w-coalesced.
//   oh tile staged via LDS (layout bridge [p][c] -> [c][w]).
//   out = gamma*(OW + OH) + x.
// ---------------------------------------------------------------------------
__global__ __launch_bounds__(256) void aggW_kernel(
    const ushort* __restrict__ attb, const ushort* __restrict__ vW,
    const ushort* __restrict__ oh, const float* __restrict__ x,
    const float* __restrict__ gamma, float* __restrict__ out)
{
    __shared__ ushort As[96 * 104];    // AW[w][u]
    __shared__ ushort Bs[64 * 104];    // vW c-tile [c][u]
    __shared__ ushort Os[96 * 72];     // oh tile [w][cl]
    const int b = blockIdx.y, h = blockIdx.x, tid = threadIdx.x;
    const float gm = gamma[0];

    for (int l = tid; l < 96 * 12; l += 256) {
        int ww = l / 12, seg = l % 12;
        uint4 u = *(const uint4*)&attb[((size_t)(b * nP + h * nW + ww)) * nS
                                       + 96 + seg * 8];
        *(uint4*)&As[ww * 104 + seg * 8] = u;
    }
    const int lane = tid & 63, wave = tid >> 6;
    const int wr = wave & 1, wc = wave >> 1;   // wr: w-half, wc: c-half
    const int lm = lane & 15, q = lane >> 4;
    int coff[2], woff[3];
    #pragma unroll
    for (int i = 0; i < 2; ++i) coff[i] = (wc * 32 + i * 16 + lm) * 104 + q * 8;
    #pragma unroll
    for (int j = 0; j < 3; ++j) woff[j] = (wr * 48 + j * 16 + lm) * 104 + q * 8;

    for (int ct = 0; ct < 8; ++ct) {
        if (ct) __syncthreads();
        for (int l = tid; l < 64 * 12; l += 256) {
            int cl = l / 12, seg = l % 12;
            uint4 u = *(const uint4*)&vW[((size_t)(b * nC + ct * 64 + cl)) * nP
                                         + h * nW + seg * 8];
            *(uint4*)&Bs[cl * 104 + seg * 8] = u;
        }
        for (int l = tid; l < 96 * 8; l += 256) {
            int ww = l / 8, seg = l % 8;
            uint4 u = *(const uint4*)&oh[((size_t)(b * nP + h * nW + ww)) * nC
                                         + ct * 64 + seg * 8];
            *(uint4*)&Os[ww * 72 + seg * 8] = u;
        }
        __syncthreads();
        floatx4 acc[2][3];
        #pragma unroll
        for (int i = 0; i < 2; ++i)
            #pragma unroll
            for (int j = 0; j < 3; ++j) acc[i][j] = (floatx4){0.f, 0.f, 0.f, 0.f};
        #pragma unroll
        for (int ks = 0; ks < 3; ++ks) {
            short8 cv[2], wv[3];
            #pragma unroll
            for (int i = 0; i < 2; ++i) cv[i] = *(const short8*)&Bs[coff[i] + ks * 32];
            #pragma unroll
            for (int j = 0; j < 3; ++j) wv[j] = *(const short8*)&As[woff[j] + ks * 32];
            #pragma unroll
            for (int i = 0; i < 2; ++i)
                #pragma unroll
                for (int j = 0; j < 3; ++j)
                    acc[i][j] = __builtin_amdgcn_mfma_f32_16x16x32_bf16(
                        cv[i], wv[j], acc[i][j], 0, 0, 0);
        }
        // D: row(q*4+r)=c, col(lm)=w
        #pragma unroll
        for (int i = 0; i < 2; ++i) {
            #pragma unroll
            for (int r = 0; r < 4; ++r) {
                int cl = wc * 32 + i * 16 + q * 4 + r;
                int c  = ct * 64 + cl;
                #pragma unroll
                for (int j = 0; j < 3; ++j) {
                    int ww = wr * 48 + j * 16 + lm;
                    size_t oidx = ((size_t)(b * nC + c) * nH + h) * nW + ww;
                    float ohv = bf2f(Os[ww * 72 + cl]);
                    out[oidx] = gm * (acc[i][j][r] + ohv) + x[oidx];
                }
            }
        }
    }
}

// ---------------------------------------------------------------------------
extern "C" void kernel_launch(void* const* d_in, const int* in_sizes, int n_in,
                              void* d_out, int out_size, void* d_ws, size_t ws_size,
                              hipStream_t stream)
{
    const float* x     = (const float*)d_in[0];
    const float* Wq    = (const float*)d_in[1];
    const float* bq    = (const float*)d_in[2];
    const float* Wk    = (const float*)d_in[3];
    const float* bk    = (const float*)d_in[4];
    const float* Wv    = (const float*)d_in[5];
    const float* bv    = (const float*)d_in[6];
    const float* gamma = (const float*)d_in[7];
    float* out = (float*)d_out;

    // Workspace layout (349.2 MB):
    //  R1 [nM*nC bf16 = 75.5MB]: xT until proj done, then vH (vtrans output)
    //  R2 [nM*128 f32 = 37.7MB]: qk
    //  R3 [nM*nC bf16 = 75.5MB]: vW
    //  R4 [nM*nS f32  = 56.6MB]: Wc+bc (bf16 weights) until scores, then att
    //  R5 [nM*nS bf16 = 28.3MB]: attb
    //  R6 [nM*nC bf16 = 75.5MB]: oh
    char* p = (char*)d_ws;
    ushort* xT  = (ushort*)p;
    ushort* vH  = (ushort*)p;
    p += (size_t)nM * nC * 2;
    float* qk   = (float*)p;
    p += (size_t)nM * 128 * 4;
    ushort* vW  = (ushort*)p;
    p += (size_t)nM * nC * 2;
    float* att  = (float*)p;
    ushort* Wc  = (ushort*)p;
    float* bc   = (float*)(p + (size_t)nO * nC * 2);
    p += (size_t)nM * nS * 4;
    ushort* attb = (ushort*)p;
    p += (size_t)nM * nS * 2;
    ushort* oh  = (ushort*)p;

    dim3 blk(256);
    transpose_kernel<<<dim3(nP / 64, nC / 64, nB), blk, 0, stream>>>(x, xT);
    wconv_kernel<<<dim3(nO), blk, 0, stream>>>(Wq, bq, Wk, bk, Wv, bv, Wc, bc);
    mfma_proj_kernel<<<dim3((nM / 128) * (nO / 128)), blk, 0, stream>>>(xT, Wc, bc, qk, vW);
    vtrans_kernel<<<dim3(nC, nB), blk, 0, stream>>>(vW, vH);
    score_kernel<<<dim3(nW, nB), blk, 0, stream>>>(qk, att, 0);
    score_kernel<<<dim3(nH, nB), blk, 0, stream>>>(qk, att, 1);
    softmax_kernel<<<dim3(nB * nP / 4), blk, 0, stream>>>(att, attb);
    aggH_kernel<<<dim3(nW, nB), blk, 0, stream>>>(attb, vH, oh);
    aggW_kernel<<<dim3(nH, nB), blk, 0, stream>>>(attb, vW, oh, x, gamma, out);
}

// Round 4
// 573.693 us; speedup vs baseline: 1.0231x; 1.0045x over previous
//
#include <hip/hip_runtime.h>
#include <math.h>

// Problem constants (fixed by reference)
constexpr int nB = 8;
constexpr int nC = 512;
constexpr int nH = 96;
constexpr int nW = 96;
constexpr int nP = nH * nW;        // 9216 pixels per batch
constexpr int nCQK = 64;           // q/k channels
constexpr int nS = nH + nW;        // 192 softmax width
constexpr int nO = 640;            // fused q(64)|k(64)|v(512)
constexpr int nM = nB * nP;        // 73728 total pixels

using short8  = __attribute__((ext_vector_type(8))) short;
using ushort8 = __attribute__((ext_vector_type(8))) unsigned short;
using floatx4 = __attribute__((ext_vector_type(4))) float;

__device__ inline unsigned pack_bf16(float a, float b) {
    unsigned ua = __float_as_uint(a), ub = __float_as_uint(b);
    ua = (ua + 0x7fff + ((ua >> 16) & 1)) >> 16;   // RNE
    ub = (ub + 0x7fff + ((ub >> 16) & 1)) >> 16;
    return ua | (ub << 16);
}
__device__ inline ushort f2bf(float a) {
    unsigned ua = __float_as_uint(a);
    return (ushort)((ua + 0x7fff + ((ua >> 16) & 1)) >> 16);
}
__device__ inline float bf2f(ushort u) {
    return __uint_as_float((unsigned)u << 16);
}

// async global->LDS, 16B per lane. LDS dest = wave-uniform base + lane*16.
typedef __attribute__((address_space(3))) unsigned int lds_u32;
typedef __attribute__((address_space(1))) const unsigned int glb_u32;
__device__ inline void gl_lds16(const void* g, void* l) {
    __builtin_amdgcn_global_load_lds((glb_u32*)g, (lds_u32*)l, 16, 0, 0);
}

// ---------------------------------------------------------------------------
// T1: x[b][c][p] fp32  ->  xT[b*nP+p][c] bf16   (64c x 64p LDS tile)
// ---------------------------------------------------------------------------
__global__ __launch_bounds__(256) void transpose_kernel(
    const float* __restrict__ x, ushort* __restrict__ xT)
{
    __shared__ float T[64 * 65];
    const int b = blockIdx.z, p0 = blockIdx.x * 64, c0 = blockIdx.y * 64;
    const int tid = threadIdx.x;
    #pragma unroll
    for (int it = 0; it < 4; ++it) {
        int c  = it * 16 + (tid >> 4);
        int p4 = (tid & 15) * 4;
        float4 v = *(const float4*)&x[((size_t)b * nC + c0 + c) * nP + p0 + p4];
        T[c * 65 + p4 + 0] = v.x; T[c * 65 + p4 + 1] = v.y;
        T[c * 65 + p4 + 2] = v.z; T[c * 65 + p4 + 3] = v.w;
    }
    __syncthreads();
    #pragma unroll
    for (int it = 0; it < 8; ++it) {
        int idx = it * 256 + tid;
        int p = idx >> 5;              // 0..63
        int c = (idx & 31) * 2;        // even c
        unsigned u = pack_bf16(T[c * 65 + p], T[(c + 1) * 65 + p]);
        *(unsigned*)&xT[((size_t)b * nP + p0 + p) * nC + c0 + c] = u;
    }
}

// ---------------------------------------------------------------------------
// T2: weights -> bf16 Wc[640][512], bias -> bc[640]. One block per o-row.
// ---------------------------------------------------------------------------
__global__ __launch_bounds__(256) void wconv_kernel(
    const float* __restrict__ Wq, const float* __restrict__ bq,
    const float* __restrict__ Wk, const float* __restrict__ bk,
    const float* __restrict__ Wv, const float* __restrict__ bv,
    ushort* __restrict__ Wc, float* __restrict__ bc)
{
    const int o = blockIdx.x, t = threadIdx.x;
    const float *src, *bsrc; int oo;
    if (o < 64)       { src = Wq; bsrc = bq; oo = o; }
    else if (o < 128) { src = Wk; bsrc = bk; oo = o - 64; }
    else              { src = Wv; bsrc = bv; oo = o - 128; }
    float2 v = *(const float2*)&src[(size_t)oo * nC + t * 2];
    *(unsigned*)&Wc[(size_t)o * nC + t * 2] = pack_bf16(v.x, v.y);
    if (t == 0) bc[o] = bsrc[oo];
}

// ---------------------------------------------------------------------------
// G: fused QKV projection via MFMA.
// T4 counted-vmcnt 3-buffer pipeline: stage tiles t..t+2 stay in flight;
// per K-step: s_waitcnt vmcnt(4) (oldest stage only) -> raw s_barrier ->
// issue stage t+2 -> ds_read+MFMA tile t. Loads get ~2 K-steps to land.
// ds_read bank fix (rule #21 both-sides swizzle): linear gl_lds16 dest +
// inverse-swizzled GLOBAL source chunk + swizzled READ offset,
// chunk' = chunk ^ ((row>>1)&3)  -> 8-way conflict becomes 2-way (free).
// 1D grid, ntile fastest + XCD swizzle (FETCH ~44 MB, L3-resident).
// ntile==0: qk[m][o(0..127)] fp32 ; ntile>=1: swapped operands ->
//           D[c][m] -> vW[b][c][h][w] bf16 coalesced in pixel.
// ---------------------------------------------------------------------------
__global__ __launch_bounds__(256) void mfma_proj_kernel(
    const ushort* __restrict__ xT, const ushort* __restrict__ Wc,
    const float* __restrict__ bc, float* __restrict__ qk,
    ushort* __restrict__ vW)
{
    __shared__ ushort As[3][128 * 32];
    __shared__ ushort Bs[3][128 * 32];
    const int tid = threadIdx.x;

    // grid: 2880 blocks = 576 mtiles x 5 ntiles, ntile fastest.
    // XCD swizzle: each XCD gets 360 consecutive wgids (72 disjoint mtiles).
    constexpr int NWG   = (nM / 128) * (nO / 128);   // 2880
    constexpr int CHUNK = NWG / 8;                   // 360
    const int bid = blockIdx.x;
    const int wg  = (bid & 7) * CHUNK + (bid >> 3);
    const int mtile = wg / 5, ntile = wg % 5;
    const int m0 = mtile * 128, o0 = ntile * 128;

    const int lane = tid & 63;
    const int wave = tid >> 6;

    // staging: lane covers row wave*16 + (lane>>2); GLOBAL 16B-chunk index is
    // pre-swizzled: chunk = (lane&3) ^ ((lane>>3)&3)  (inverse of read swz,
    // since (row>>1)&3 == (lane>>3)&3 for row = wave*16 + (lane>>2)).
    const int srow = wave * 16 + (lane >> 2);
    const int schk = ((lane & 3) ^ ((lane >> 3) & 3)) * 8;
    const ushort* gA0 = xT + (size_t)(m0 + srow) * nC + schk;
    const ushort* gA1 = gA0 + (size_t)64 * nC;
    const ushort* gB0 = Wc + (size_t)(o0 + srow) * nC + schk;
    const ushort* gB1 = gB0 + (size_t)64 * nC;
    const int lbase  = wave * 16 * 32;          // wave-uniform LDS row base
    const int lbase1 = lbase + 64 * 32;

    const int wr = wave & 1, wcl = wave >> 1;
    const int lm = lane & 15, q = lane >> 4;
    // read: row R = (half)*64 + i*16 + lm; chunk q stored at q ^ ((R>>1)&3)
    const int rsw = (lm >> 1) & 3;              // (R>>1)&3 == (lm>>1)&3
    int aoff[4], boff[4];
    #pragma unroll
    for (int i = 0; i < 4; ++i)
        aoff[i] = (wr * 64 + i * 16 + lm) * 32 + ((q ^ rsw) * 8);
    #pragma unroll
    for (int j = 0; j < 4; ++j)
        boff[j] = (wcl * 64 + j * 16 + lm) * 32 + ((q ^ rsw) * 8);

    floatx4 acc[4][4];
    #pragma unroll
    for (int i = 0; i < 4; ++i)
        #pragma unroll
        for (int j = 0; j < 4; ++j) acc[i][j] = (floatx4){0.f, 0.f, 0.f, 0.f};

    const bool vmode = (ntile != 0);

    // prologue: stage K-steps 0 and 1 (8 loads in flight)
    gl_lds16(gA0, &As[0][lbase]); gl_lds16(gA1, &As[0][lbase1]);
    gl_lds16(gB0, &Bs[0][lbase]); gl_lds16(gB1, &Bs[0][lbase1]);
    gl_lds16(gA0 + 32, &As[1][lbase]); gl_lds16(gA1 + 32, &As[1][lbase1]);
    gl_lds16(gB0 + 32, &Bs[1][lbase]); gl_lds16(gB1 + 32, &Bs[1][lbase1]);

    #pragma unroll
    for (int t = 0; t < 16; ++t) {
        // wait for the OLDEST stage only; keep the next one in flight
        if (t < 15) asm volatile("s_waitcnt vmcnt(4)" ::: "memory");
        else        asm volatile("s_waitcnt vmcnt(0)" ::: "memory");
        __builtin_amdgcn_s_barrier();
        __builtin_amdgcn_sched_barrier(0);
        if (t < 14) {                    // stage t+2 into the retiring buffer
            const int nb = (t + 2) % 3;
            const int k0 = (t + 2) * 32;
            gl_lds16(gA0 + k0, &As[nb][lbase]);
            gl_lds16(gA1 + k0, &As[nb][lbase1]);
            gl_lds16(gB0 + k0, &Bs[nb][lbase]);
            gl_lds16(gB1 + k0, &Bs[nb][lbase1]);
        }
        const int cur = t % 3;
        short8 av[4], bvv[4];
        #pragma unroll
        for (int i = 0; i < 4; ++i) av[i] = *(const short8*)&As[cur][aoff[i]];
        #pragma unroll
        for (int j = 0; j < 4; ++j) bvv[j] = *(const short8*)&Bs[cur][boff[j]];
        if (!vmode) {
            #pragma unroll
            for (int i = 0; i < 4; ++i)
                #pragma unroll
                for (int j = 0; j < 4; ++j)
                    acc[i][j] = __builtin_amdgcn_mfma_f32_16x16x32_bf16(
                        av[i], bvv[j], acc[i][j], 0, 0, 0);
        } else {
            // swapped: D rows = Wc-row (o/c), D cols = xT-row (m)
            #pragma unroll
            for (int i = 0; i < 4; ++i)
                #pragma unroll
                for (int j = 0; j < 4; ++j)
                    acc[i][j] = __builtin_amdgcn_mfma_f32_16x16x32_bf16(
                        bvv[i], av[j], acc[i][j], 0, 0, 0);
        }
    }

    if (!vmode) {
        // D: col(lm)=o, row(q*4+r)=m
        float bj[4];
        #pragma unroll
        for (int j = 0; j < 4; ++j) bj[j] = bc[wcl * 64 + j * 16 + lm];
        #pragma unroll
        for (int i = 0; i < 4; ++i) {
            #pragma unroll
            for (int r = 0; r < 4; ++r) {
                int mrow = m0 + wr * 64 + i * 16 + q * 4 + r;
                float* orow = qk + (size_t)mrow * 128 + wcl * 64 + lm;
                #pragma unroll
                for (int j = 0; j < 4; ++j) orow[j * 16] = acc[i][j][r] + bj[j];
            }
        }
    } else {
        // D: row(q*4+r)=o (c), col(lm)=m (pixel)
        const int b  = m0 / nP;
        const int p0 = m0 - b * nP;
        #pragma unroll
        for (int i = 0; i < 4; ++i) {
            #pragma unroll
            for (int r = 0; r < 4; ++r) {
                int o = o0 + wcl * 64 + i * 16 + q * 4 + r;
                float bias = bc[o];
                int c = o - 128;
                ushort* vrow = vW + ((size_t)(b * nC + c)) * nP + p0 + wr * 64 + lm;
                #pragma unroll
                for (int j = 0; j < 4; ++j)
                    vrow[j * 16] = f2bf(acc[i][j][r] + bias);
            }
        }
    }
}

// ---------------------------------------------------------------------------
// vtrans: vW[b][c][h][w] -> vH[b][c][w][h]  (bf16 96x96 spatial transpose)
// XOR-swizzled 16-chunk rows so the column gather is bank-conflict-free.
// ---------------------------------------------------------------------------
__global__ __launch_bounds__(256) void vtrans_kernel(
    const ushort* __restrict__ vW, ushort* __restrict__ vH)
{
    __shared__ ushort T[96 * 128];
    const int c = blockIdx.x, b = blockIdx.y, tid = threadIdx.x;
    const size_t base = ((size_t)(b * nC + c)) * nP;
    for (int l = tid; l < 96 * 12; l += 256) {
        int hh = l / 12, seg = l % 12;
        uint4 u = *(const uint4*)&vW[base + (size_t)hh * nW + seg * 8];
        *(uint4*)&T[hh * 128 + ((seg ^ ((hh >> 3) & 7)) * 8)] = u;
    }
    __syncthreads();
    for (int l = tid; l < 96 * 12; l += 256) {
        int ww = l / 12, seg = l % 12;
        ushort8 vv;
        #pragma unroll
        for (int e = 0; e < 8; ++e) {
            int hh = seg * 8 + e;
            int phys = (((ww >> 3) ^ ((hh >> 3) & 7)) * 8) + (ww & 7);
            vv[e] = T[hh * 128 + phys];
        }
        *(ushort8*)&vH[base + (size_t)ww * nH + seg * 8] = vv;
    }
}

// ---------------------------------------------------------------------------
// scores: mode 0 (H): per (b,w) -> eH[h][g], diag=-inf ; mode 1 (W): per (b,h)
// q/k read from qk[m][128] fp32 (offsets 0 / 64).
// ---------------------------------------------------------------------------
__global__ __launch_bounds__(256) void score_kernel(
    const float* __restrict__ qk, float* __restrict__ att, int mode)
{
    __shared__ float Qs[96][68];
    __shared__ float Ks[96][68];
    const int b   = blockIdx.y;
    const int fix = blockIdx.x;
    const int tid = threadIdx.x;

    for (int l = tid; l < 96 * 16; l += 256) {
        int r  = l / 16;
        int c4 = (l % 16) * 4;
        size_t p = (mode == 0) ? ((size_t)r * nW + fix) : ((size_t)fix * nW + r);
        const float* row = &qk[((size_t)b * nP + p) * 128];
        *(float4*)&Qs[r][c4] = *(const float4*)&row[c4];
        *(float4*)&Ks[r][c4] = *(const float4*)&row[64 + c4];
    }
    __syncthreads();

    const int tx = tid % 16;
    const int ty = tid / 16;
    float acc[6][6] = {};
    for (int c4 = 0; c4 < nCQK; c4 += 4) {
        float4 qv[6], kv[6];
        #pragma unroll
        for (int i = 0; i < 6; ++i) qv[i] = *(const float4*)&Qs[ty + 16 * i][c4];
        #pragma unroll
        for (int j = 0; j < 6; ++j) kv[j] = *(const float4*)&Ks[tx + 16 * j][c4];
        #pragma unroll
        for (int i = 0; i < 6; ++i)
            #pragma unroll
            for (int j = 0; j < 6; ++j)
                acc[i][j] += qv[i].x * kv[j].x + qv[i].y * kv[j].y
                           + qv[i].z * kv[j].z + qv[i].w * kv[j].w;
    }

    #pragma unroll
    for (int i = 0; i < 6; ++i) {
        int row = ty + 16 * i;
        #pragma unroll
        for (int j = 0; j < 6; ++j) {
            int col = tx + 16 * j;
            float val = acc[i][j];
            if (mode == 0) {
                if (col == row) val = -INFINITY;
                att[((size_t)b * nP + row * nW + fix) * nS + col] = val;
            } else {
                att[((size_t)b * nP + fix * nW + row) * nS + 96 + col] = val;
            }
        }
    }
}

// ---------------------------------------------------------------------------
// softmax over 192 entries per pixel; fp32 in, bf16 out. One wave per pixel.
// ---------------------------------------------------------------------------
__global__ __launch_bounds__(256) void softmax_kernel(
    const float* __restrict__ att, ushort* __restrict__ attb)
{
    const int wav  = threadIdx.x / 64;
    const int lane = threadIdx.x % 64;
    const size_t pix = (size_t)blockIdx.x * 4 + wav;
    const float* a = att + pix * nS;
    ushort* ab = attb + pix * nS;
    float v0 = a[lane], v1 = a[lane + 64], v2 = a[lane + 128];
    float m = fmaxf(fmaxf(v0, v1), v2);
    #pragma unroll
    for (int off = 32; off; off >>= 1) m = fmaxf(m, __shfl_xor(m, off));
    float e0 = __expf(v0 - m), e1 = __expf(v1 - m), e2 = __expf(v2 - m);
    float s = e0 + e1 + e2;
    #pragma unroll
    for (int off = 32; off; off >>= 1) s += __shfl_xor(s, off);
    float inv = 1.0f / s;
    ab[lane]       = f2bf(e0 * inv);
    ab[lane + 64]  = f2bf(e1 * inv);
    ab[lane + 128] = f2bf(e2 * inv);
}

// ---------------------------------------------------------------------------
// aggH (MFMA): per (b,w): OH[h][c] = sum_g AH[h][g] * vH[c][g]
//   A = attb rows (H half, g-contig); B = vH rows (g-contig).
//   D rows=h, cols=c -> oh[b,p(h,w)][c] bf16, c-coalesced stores.
// ---------------------------------------------------------------------------
__global__ __launch_bounds__(256) void aggH_kernel(
    const ushort* __restrict__ attb, const ushort* __restrict__ vH,
    ushort* __restrict__ oh)
{
    __shared__ ushort As[96 * 104];    // AH[h][g]
    __shared__ ushort Bs[128 * 104];   // vH c-tile [c][g]
    const int b = blockIdx.y, w = blockIdx.x, tid = threadIdx.x;

    for (int l = tid; l < 96 * 12; l += 256) {
        int h = l / 12, seg = l % 12;
        uint4 u = *(const uint4*)&attb[((size_t)(b * nP + h * nW + w)) * nS + seg * 8];
        *(uint4*)&As[h * 104 + seg * 8] = u;
    }
    const int lane = tid & 63, wave = tid >> 6;
    const int wr = wave & 1, wc = wave >> 1;
    const int lm = lane & 15, q = lane >> 4;
    int aoff[3], boff[4];
    #pragma unroll
    for (int i = 0; i < 3; ++i) aoff[i] = (wr * 48 + i * 16 + lm) * 104 + q * 8;
    #pragma unroll
    for (int j = 0; j < 4; ++j) boff[j] = (wc * 64 + j * 16 + lm) * 104 + q * 8;

    for (int ct = 0; ct < 4; ++ct) {
        if (ct) __syncthreads();
        for (int l = tid; l < 128 * 12; l += 256) {
            int cl = l / 12, seg = l % 12;
            uint4 u = *(const uint4*)&vH[((size_t)(b * nC + ct * 128 + cl)) * nP
                                         + w * nH + seg * 8];
            *(uint4*)&Bs[cl * 104 + seg * 8] = u;
        }
        __syncthreads();
        floatx4 acc[3][4];
        #pragma unroll
        for (int i = 0; i < 3; ++i)
            #pragma unroll
            for (int j = 0; j < 4; ++j) acc[i][j] = (floatx4){0.f, 0.f, 0.f, 0.f};
        #pragma unroll
        for (int ks = 0; ks < 3; ++ks) {
            short8 av[3], bvv[4];
            #pragma unroll
            for (int i = 0; i < 3; ++i) av[i] = *(const short8*)&As[aoff[i] + ks * 32];
            #pragma unroll
            for (int j = 0; j < 4; ++j) bvv[j] = *(const short8*)&Bs[boff[j] + ks * 32];
            #pragma unroll
            for (int i = 0; i < 3; ++i)
                #pragma unroll
                for (int j = 0; j < 4; ++j)
                    acc[i][j] = __builtin_amdgcn_mfma_f32_16x16x32_bf16(
                        av[i], bvv[j], acc[i][j], 0, 0, 0);
        }
        #pragma unroll
        for (int i = 0; i < 3; ++i) {
            #pragma unroll
            for (int r = 0; r < 4; ++r) {
                int h = wr * 48 + i * 16 + q * 4 + r;
                ushort* orow = oh + ((size_t)(b * nP + h * nW + w)) * nC
                               + ct * 128 + wc * 64 + lm;
                #pragma unroll
                for (int j = 0; j < 4; ++j) orow[j * 16] = f2bf(acc[i][j][r]);
            }
        }
    }
}

// ---------------------------------------------------------------------------
// aggW (MFMA) + epilogue: per (b,h): OW[w][c] = sum_u AW[w][u] * vW[c][u]
//   swapped operands -> D rows=c, cols=w; out NCHW is w-coalesced.
//   oh tile staged via LDS (layout bridge [p][c] -> [c][w]).
//   out = gamma*(OW + OH) + x.
// ---------------------------------------------------------------------------
__global__ __launch_bounds__(256) void aggW_kernel(
    const ushort* __restrict__ attb, const ushort* __restrict__ vW,
    const ushort* __restrict__ oh, const float* __restrict__ x,
    const float* __restrict__ gamma, float* __restrict__ out)
{
    __shared__ ushort As[96 * 104];    // AW[w][u]
    __shared__ ushort Bs[64 * 104];    // vW c-tile [c][u]
    __shared__ ushort Os[96 * 72];     // oh tile [w][cl]
    const int b = blockIdx.y, h = blockIdx.x, tid = threadIdx.x;
    const float gm = gamma[0];

    for (int l = tid; l < 96 * 12; l += 256) {
        int ww = l / 12, seg = l % 12;
        uint4 u = *(const uint4*)&attb[((size_t)(b * nP + h * nW + ww)) * nS
                                       + 96 + seg * 8];
        *(uint4*)&As[ww * 104 + seg * 8] = u;
    }
    const int lane = tid & 63, wave = tid >> 6;
    const int wr = wave & 1, wc = wave >> 1;   // wr: w-half, wc: c-half
    const int lm = lane & 15, q = lane >> 4;
    int coff[2], woff[3];
    #pragma unroll
    for (int i = 0; i < 2; ++i) coff[i] = (wc * 32 + i * 16 + lm) * 104 + q * 8;
    #pragma unroll
    for (int j = 0; j < 3; ++j) woff[j] = (wr * 48 + j * 16 + lm) * 104 + q * 8;

    for (int ct = 0; ct < 8; ++ct) {
        if (ct) __syncthreads();
        for (int l = tid; l < 64 * 12; l += 256) {
            int cl = l / 12, seg = l % 12;
            uint4 u = *(const uint4*)&vW[((size_t)(b * nC + ct * 64 + cl)) * nP
                                         + h * nW + seg * 8];
            *(uint4*)&Bs[cl * 104 + seg * 8] = u;
        }
        for (int l = tid; l < 96 * 8; l += 256) {
            int ww = l / 8, seg = l % 8;
            uint4 u = *(const uint4*)&oh[((size_t)(b * nP + h * nW + ww)) * nC
                                         + ct * 64 + seg * 8];
            *(uint4*)&Os[ww * 72 + seg * 8] = u;
        }
        __syncthreads();
        floatx4 acc[2][3];
        #pragma unroll
        for (int i = 0; i < 2; ++i)
            #pragma unroll
            for (int j = 0; j < 3; ++j) acc[i][j] = (floatx4){0.f, 0.f, 0.f, 0.f};
        #pragma unroll
        for (int ks = 0; ks < 3; ++ks) {
            short8 cv[2], wv[3];
            #pragma unroll
            for (int i = 0; i < 2; ++i) cv[i] = *(const short8*)&Bs[coff[i] + ks * 32];
            #pragma unroll
            for (int j = 0; j < 3; ++j) wv[j] = *(const short8*)&As[woff[j] + ks * 32];
            #pragma unroll
            for (int i = 0; i < 2; ++i)
                #pragma unroll
                for (int j = 0; j < 3; ++j)
                    acc[i][j] = __builtin_amdgcn_mfma_f32_16x16x32_bf16(
                        cv[i], wv[j], acc[i][j], 0, 0, 0);
        }
        // D: row(q*4+r)=c, col(lm)=w
        #pragma unroll
        for (int i = 0; i < 2; ++i) {
            #pragma unroll
            for (int r = 0; r < 4; ++r) {
                int cl = wc * 32 + i * 16 + q * 4 + r;
                int c  = ct * 64 + cl;
                #pragma unroll
                for (int j = 0; j < 3; ++j) {
                    int ww = wr * 48 + j * 16 + lm;
                    size_t oidx = ((size_t)(b * nC + c) * nH + h) * nW + ww;
                    float ohv = bf2f(Os[ww * 72 + cl]);
                    out[oidx] = gm * (acc[i][j][r] + ohv) + x[oidx];
                }
            }
        }
    }
}

// ---------------------------------------------------------------------------
extern "C" void kernel_launch(void* const* d_in, const int* in_sizes, int n_in,
                              void* d_out, int out_size, void* d_ws, size_t ws_size,
                              hipStream_t stream)
{
    const float* x     = (const float*)d_in[0];
    const float* Wq    = (const float*)d_in[1];
    const float* bq    = (const float*)d_in[2];
    const float* Wk    = (const float*)d_in[3];
    const float* bk    = (const float*)d_in[4];
    const float* Wv    = (const float*)d_in[5];
    const float* bv    = (const float*)d_in[6];
    const float* gamma = (const float*)d_in[7];
    float* out = (float*)d_out;

    // Workspace layout (349.2 MB):
    //  R1 [nM*nC bf16 = 75.5MB]: xT until proj done, then vH (vtrans output)
    //  R2 [nM*128 f32 = 37.7MB]: qk
    //  R3 [nM*nC bf16 = 75.5MB]: vW
    //  R4 [nM*nS f32  = 56.6MB]: Wc+bc (bf16 weights) until scores, then att
    //  R5 [nM*nS bf16 = 28.3MB]: attb
    //  R6 [nM*nC bf16 = 75.5MB]: oh
    char* p = (char*)d_ws;
    ushort* xT  = (ushort*)p;
    ushort* vH  = (ushort*)p;
    p += (size_t)nM * nC * 2;
    float* qk   = (float*)p;
    p += (size_t)nM * 128 * 4;
    ushort* vW  = (ushort*)p;
    p += (size_t)nM * nC * 2;
    float* att  = (float*)p;
    ushort* Wc  = (ushort*)p;
    float* bc   = (float*)(p + (size_t)nO * nC * 2);
    p += (size_t)nM * nS * 4;
    ushort* attb = (ushort*)p;
    p += (size_t)nM * nS * 2;
    ushort* oh  = (ushort*)p;

    dim3 blk(256);
    transpose_kernel<<<dim3(nP / 64, nC / 64, nB), blk, 0, stream>>>(x, xT);
    wconv_kernel<<<dim3(nO), blk, 0, stream>>>(Wq, bq, Wk, bk, Wv, bv, Wc, bc);
    mfma_proj_kernel<<<dim3((nM / 128) * (nO / 128)), blk, 0, stream>>>(xT, Wc, bc, qk, vW);
    vtrans_kernel<<<dim3(nC, nB), blk, 0, stream>>>(vW, vH);
    score_kernel<<<dim3(nW, nB), blk, 0, stream>>>(qk, att, 0);
    score_kernel<<<dim3(nH, nB), blk, 0, stream>>>(qk, att, 1);
    softmax_kernel<<<dim3(nB * nP / 4), blk, 0, stream>>>(att, attb);
    aggH_kernel<<<dim3(nW, nB), blk, 0, stream>>>(attb, vH, oh);
    aggW_kernel<<<dim3(nH, nB), blk, 0, stream>>>(attb, vW, oh, x, gamma, out);
}

// Round 6
// 567.137 us; speedup vs baseline: 1.0349x; 1.0116x over previous
//
#include <hip/hip_runtime.h>
#include <math.h>

// Problem constants (fixed by reference)
constexpr int nB = 8;
constexpr int nC = 512;
constexpr int nH = 96;
constexpr int nW = 96;
constexpr int nP = nH * nW;        // 9216 pixels per batch
constexpr int nCQK = 64;           // q/k channels
constexpr int nS = nH + nW;        // 192 softmax width
constexpr int nO = 640;            // fused q(64)|k(64)|v(512)
constexpr int nM = nB * nP;        // 73728 total pixels

using short8  = __attribute__((ext_vector_type(8))) short;
using ushort8 = __attribute__((ext_vector_type(8))) unsigned short;
using floatx4 = __attribute__((ext_vector_type(4))) float;

__device__ inline unsigned pack_bf16(float a, float b) {
    unsigned ua = __float_as_uint(a), ub = __float_as_uint(b);
    ua = (ua + 0x7fff + ((ua >> 16) & 1)) >> 16;   // RNE
    ub = (ub + 0x7fff + ((ub >> 16) & 1)) >> 16;
    return ua | (ub << 16);
}
__device__ inline ushort f2bf(float a) {
    unsigned ua = __float_as_uint(a);
    return (ushort)((ua + 0x7fff + ((ua >> 16) & 1)) >> 16);
}
__device__ inline float bf2f(ushort u) {
    return __uint_as_float((unsigned)u << 16);
}

// async global->LDS, 16B per lane. LDS dest = wave-uniform base + lane*16.
typedef __attribute__((address_space(3))) unsigned int lds_u32;
typedef __attribute__((address_space(1))) const unsigned int glb_u32;
__device__ inline void gl_lds16(const void* g, void* l) {
    __builtin_amdgcn_global_load_lds((glb_u32*)g, (lds_u32*)l, 16, 0, 0);
}

// ---------------------------------------------------------------------------
// T1: x[b][c][p] fp32  ->  xT[b*nP+p][c] bf16   (64c x 64p LDS tile)
// Output vectorized: each thread packs 8 c-values -> one 16B store.
// ---------------------------------------------------------------------------
__global__ __launch_bounds__(256) void transpose_kernel(
    const float* __restrict__ x, ushort* __restrict__ xT)
{
    __shared__ float T[64 * 65];
    const int b = blockIdx.z, p0 = blockIdx.x * 64, c0 = blockIdx.y * 64;
    const int tid = threadIdx.x;
    #pragma unroll
    for (int it = 0; it < 4; ++it) {
        int c  = it * 16 + (tid >> 4);
        int p4 = (tid & 15) * 4;
        float4 v = *(const float4*)&x[((size_t)b * nC + c0 + c) * nP + p0 + p4];
        T[c * 65 + p4 + 0] = v.x; T[c * 65 + p4 + 1] = v.y;
        T[c * 65 + p4 + 2] = v.z; T[c * 65 + p4 + 3] = v.w;
    }
    __syncthreads();
    #pragma unroll
    for (int it = 0; it < 2; ++it) {
        int idx = it * 256 + tid;      // 0..511
        int p  = idx >> 3;             // 0..63
        int cc = (idx & 7) * 8;        // 8-chunk of c
        ushort8 v;
        #pragma unroll
        for (int e = 0; e < 8; ++e) v[e] = f2bf(T[(cc + e) * 65 + p]);
        *(ushort8*)&xT[((size_t)b * nP + p0 + p) * nC + c0 + cc] = v;
    }
}

// ---------------------------------------------------------------------------
// T2: weights -> bf16 Wc[640][512], bias -> bc[640]. One block per o-row.
// ---------------------------------------------------------------------------
__global__ __launch_bounds__(256) void wconv_kernel(
    const float* __restrict__ Wq, const float* __restrict__ bq,
    const float* __restrict__ Wk, const float* __restrict__ bk,
    const float* __restrict__ Wv, const float* __restrict__ bv,
    ushort* __restrict__ Wc, float* __restrict__ bc)
{
    const int o = blockIdx.x, t = threadIdx.x;
    const float *src, *bsrc; int oo;
    if (o < 64)       { src = Wq; bsrc = bq; oo = o; }
    else if (o < 128) { src = Wk; bsrc = bk; oo = o - 64; }
    else              { src = Wv; bsrc = bv; oo = o - 128; }
    float2 v = *(const float2*)&src[(size_t)oo * nC + t * 2];
    *(unsigned*)&Wc[(size_t)o * nC + t * 2] = pack_bf16(v.x, v.y);
    if (t == 0) bc[o] = bsrc[oo];
}

// ---------------------------------------------------------------------------
// G: fused QKV projection via MFMA.
// T4 counted-vmcnt 4-buffer pipeline (3-step lookahead): per K-step wait
// vmcnt(8) (oldest stage only, 2 stages stay in flight) -> barrier ->
// issue stage t+3 -> ds_read+MFMA tile t. ~540cyc latency cover.
// Both-sides chunk swizzle (verified R4: bank conflicts = 0).
// ---------------------------------------------------------------------------
__global__ __launch_bounds__(256) void mfma_proj_kernel(
    const ushort* __restrict__ xT, const ushort* __restrict__ Wc,
    const float* __restrict__ bc, float* __restrict__ qk,
    ushort* __restrict__ vW)
{
    __shared__ ushort As[4][128 * 32];
    __shared__ ushort Bs[4][128 * 32];
    const int tid = threadIdx.x;

    constexpr int NWG   = (nM / 128) * (nO / 128);   // 2880
    constexpr int CHUNK = NWG / 8;                   // 360
    const int bid = blockIdx.x;
    const int wg  = (bid & 7) * CHUNK + (bid >> 3);
    const int mtile = wg / 5, ntile = wg % 5;
    const int m0 = mtile * 128, o0 = ntile * 128;

    const int lane = tid & 63;
    const int wave = tid >> 6;

    const int srow = wave * 16 + (lane >> 2);
    const int schk = ((lane & 3) ^ ((lane >> 3) & 3)) * 8;
    const ushort* gA0 = xT + (size_t)(m0 + srow) * nC + schk;
    const ushort* gA1 = gA0 + (size_t)64 * nC;
    const ushort* gB0 = Wc + (size_t)(o0 + srow) * nC + schk;
    const ushort* gB1 = gB0 + (size_t)64 * nC;
    const int lbase  = wave * 16 * 32;
    const int lbase1 = lbase + 64 * 32;

    const int wr = wave & 1, wcl = wave >> 1;
    const int lm = lane & 15, q = lane >> 4;
    const int rsw = (lm >> 1) & 3;
    int aoff[4], boff[4];
    #pragma unroll
    for (int i = 0; i < 4; ++i)
        aoff[i] = (wr * 64 + i * 16 + lm) * 32 + ((q ^ rsw) * 8);
    #pragma unroll
    for (int j = 0; j < 4; ++j)
        boff[j] = (wcl * 64 + j * 16 + lm) * 32 + ((q ^ rsw) * 8);

    floatx4 acc[4][4];
    #pragma unroll
    for (int i = 0; i < 4; ++i)
        #pragma unroll
        for (int j = 0; j < 4; ++j) acc[i][j] = (floatx4){0.f, 0.f, 0.f, 0.f};

    const bool vmode = (ntile != 0);

    // prologue: stage K-steps 0,1,2 (12 loads in flight)
    #pragma unroll
    for (int tt = 0; tt < 3; ++tt) {
        gl_lds16(gA0 + tt * 32, &As[tt][lbase]);
        gl_lds16(gA1 + tt * 32, &As[tt][lbase1]);
        gl_lds16(gB0 + tt * 32, &Bs[tt][lbase]);
        gl_lds16(gB1 + tt * 32, &Bs[tt][lbase1]);
    }

    #pragma unroll
    for (int t = 0; t < 16; ++t) {
        if (t <= 13)      asm volatile("s_waitcnt vmcnt(8)" ::: "memory");
        else if (t == 14) asm volatile("s_waitcnt vmcnt(4)" ::: "memory");
        else              asm volatile("s_waitcnt vmcnt(0)" ::: "memory");
        __builtin_amdgcn_s_barrier();
        __builtin_amdgcn_sched_barrier(0);
        if (t < 13) {                    // stage t+3 into the retiring buffer
            const int nb = (t + 3) & 3;
            const int k0 = (t + 3) * 32;
            gl_lds16(gA0 + k0, &As[nb][lbase]);
            gl_lds16(gA1 + k0, &As[nb][lbase1]);
            gl_lds16(gB0 + k0, &Bs[nb][lbase]);
            gl_lds16(gB1 + k0, &Bs[nb][lbase1]);
        }
        const int cur = t & 3;
        short8 av[4], bvv[4];
        #pragma unroll
        for (int i = 0; i < 4; ++i) av[i] = *(const short8*)&As[cur][aoff[i]];
        #pragma unroll
        for (int j = 0; j < 4; ++j) bvv[j] = *(const short8*)&Bs[cur][boff[j]];
        if (!vmode) {
            #pragma unroll
            for (int i = 0; i < 4; ++i)
                #pragma unroll
                for (int j = 0; j < 4; ++j)
                    acc[i][j] = __builtin_amdgcn_mfma_f32_16x16x32_bf16(
                        av[i], bvv[j], acc[i][j], 0, 0, 0);
        } else {
            // swapped: D rows = Wc-row (o/c), D cols = xT-row (m)
            #pragma unroll
            for (int i = 0; i < 4; ++i)
                #pragma unroll
                for (int j = 0; j < 4; ++j)
                    acc[i][j] = __builtin_amdgcn_mfma_f32_16x16x32_bf16(
                        bvv[i], av[j], acc[i][j], 0, 0, 0);
        }
    }

    if (!vmode) {
        // D: col(lm)=o, row(q*4+r)=m
        float bj[4];
        #pragma unroll
        for (int j = 0; j < 4; ++j) bj[j] = bc[wcl * 64 + j * 16 + lm];
        #pragma unroll
        for (int i = 0; i < 4; ++i) {
            #pragma unroll
            for (int r = 0; r < 4; ++r) {
                int mrow = m0 + wr * 64 + i * 16 + q * 4 + r;
                float* orow = qk + (size_t)mrow * 128 + wcl * 64 + lm;
                #pragma unroll
                for (int j = 0; j < 4; ++j) orow[j * 16] = acc[i][j][r] + bj[j];
            }
        }
    } else {
        // D: row(q*4+r)=o (c), col(lm)=m (pixel)
        const int b  = m0 / nP;
        const int p0 = m0 - b * nP;
        #pragma unroll
        for (int i = 0; i < 4; ++i) {
            #pragma unroll
            for (int r = 0; r < 4; ++r) {
                int o = o0 + wcl * 64 + i * 16 + q * 4 + r;
                float bias = bc[o];
                int c = o - 128;
                ushort* vrow = vW + ((size_t)(b * nC + c)) * nP + p0 + wr * 64 + lm;
                #pragma unroll
                for (int j = 0; j < 4; ++j)
                    vrow[j * 16] = f2bf(acc[i][j][r] + bias);
            }
        }
    }
}

// ---------------------------------------------------------------------------
// vtrans: vW[b][c][h][w] -> vH[b][c][w][h]  (bf16 96x96 spatial transpose)
// ---------------------------------------------------------------------------
__global__ __launch_bounds__(256) void vtrans_kernel(
    const ushort* __restrict__ vW, ushort* __restrict__ vH)
{
    __shared__ ushort T[96 * 128];
    const int c = blockIdx.x, b = blockIdx.y, tid = threadIdx.x;
    const size_t base = ((size_t)(b * nC + c)) * nP;
    for (int l = tid; l < 96 * 12; l += 256) {
        int hh = l / 12, seg = l % 12;
        uint4 u = *(const uint4*)&vW[base + (size_t)hh * nW + seg * 8];
        *(uint4*)&T[hh * 128 + ((seg ^ ((hh >> 3) & 7)) * 8)] = u;
    }
    __syncthreads();
    for (int l = tid; l < 96 * 12; l += 256) {
        int ww = l / 12, seg = l % 12;
        ushort8 vv;
        #pragma unroll
        for (int e = 0; e < 8; ++e) {
            int hh = seg * 8 + e;
            int phys = (((ww >> 3) ^ ((hh >> 3) & 7)) * 8) + (ww & 7);
            vv[e] = T[hh * 128 + phys];
        }
        *(ushort8*)&vH[base + (size_t)ww * nH + seg * 8] = vv;
    }
}

// ---------------------------------------------------------------------------
// scores: mode 0 (H): per (b,w) -> eH[h][g], diag=-inf ; mode 1 (W): per (b,h)
// ---------------------------------------------------------------------------
__global__ __launch_bounds__(256) void score_kernel(
    const float* __restrict__ qk, float* __restrict__ att, int mode)
{
    __shared__ float Qs[96][68];
    __shared__ float Ks[96][68];
    const int b   = blockIdx.y;
    const int fix = blockIdx.x;
    const int tid = threadIdx.x;

    for (int l = tid; l < 96 * 16; l += 256) {
        int r  = l / 16;
        int c4 = (l % 16) * 4;
        size_t p = (mode == 0) ? ((size_t)r * nW + fix) : ((size_t)fix * nW + r);
        const float* row = &qk[((size_t)b * nP + p) * 128];
        *(float4*)&Qs[r][c4] = *(const float4*)&row[c4];
        *(float4*)&Ks[r][c4] = *(const float4*)&row[64 + c4];
    }
    __syncthreads();

    const int tx = tid % 16;
    const int ty = tid / 16;
    float acc[6][6] = {};
    for (int c4 = 0; c4 < nCQK; c4 += 4) {
        float4 qv[6], kv[6];
        #pragma unroll
        for (int i = 0; i < 6; ++i) qv[i] = *(const float4*)&Qs[ty + 16 * i][c4];
        #pragma unroll
        for (int j = 0; j < 6; ++j) kv[j] = *(const float4*)&Ks[tx + 16 * j][c4];
        #pragma unroll
        for (int i = 0; i < 6; ++i)
            #pragma unroll
            for (int j = 0; j < 6; ++j)
                acc[i][j] += qv[i].x * kv[j].x + qv[i].y * kv[j].y
                           + qv[i].z * kv[j].z + qv[i].w * kv[j].w;
    }

    #pragma unroll
    for (int i = 0; i < 6; ++i) {
        int row = ty + 16 * i;
        #pragma unroll
        for (int j = 0; j < 6; ++j) {
            int col = tx + 16 * j;
            float val = acc[i][j];
            if (mode == 0) {
                if (col == row) val = -INFINITY;
                att[((size_t)b * nP + row * nW + fix) * nS + col] = val;
            } else {
                att[((size_t)b * nP + fix * nW + row) * nS + 96 + col] = val;
            }
        }
    }
}

// ---------------------------------------------------------------------------
// softmax over 192 entries per pixel; fp32 in, bf16 out. One wave per pixel.
// ---------------------------------------------------------------------------
__global__ __launch_bounds__(256) void softmax_kernel(
    const float* __restrict__ att, ushort* __restrict__ attb)
{
    const int wav  = threadIdx.x / 64;
    const int lane = threadIdx.x % 64;
    const size_t pix = (size_t)blockIdx.x * 4 + wav;
    const float* a = att + pix * nS;
    ushort* ab = attb + pix * nS;
    float v0 = a[lane], v1 = a[lane + 64], v2 = a[lane + 128];
    float m = fmaxf(fmaxf(v0, v1), v2);
    #pragma unroll
    for (int off = 32; off; off >>= 1) m = fmaxf(m, __shfl_xor(m, off));
    float e0 = __expf(v0 - m), e1 = __expf(v1 - m), e2 = __expf(v2 - m);
    float s = e0 + e1 + e2;
    #pragma unroll
    for (int off = 32; off; off >>= 1) s += __shfl_xor(s, off);
    float inv = 1.0f / s;
    ab[lane]       = f2bf(e0 * inv);
    ab[lane + 64]  = f2bf(e1 * inv);
    ab[lane + 128] = f2bf(e2 * inv);
}

// ---------------------------------------------------------------------------
// aggH (MFMA): per (b,w): OH[h][c] = sum_g AH[h][g] * vH[c][g]
// Epilogue repack: acc -> LDS Ot[h][cl] (stride 136, overlays Bs) ->
// ushort8 16B coalesced stores (was 48 scalar 2B stores/thread/ct).
// ---------------------------------------------------------------------------
__global__ __launch_bounds__(256) void aggH_kernel(
    const ushort* __restrict__ attb, const ushort* __restrict__ vH,
    ushort* __restrict__ oh)
{
    __shared__ ushort As[96 * 104];    // AH[h][g]
    __shared__ ushort Bs[128 * 104];   // vH c-tile [c][g]; reused as Ot[96][136]
    ushort* Ot = Bs;
    const int b = blockIdx.y, w = blockIdx.x, tid = threadIdx.x;

    for (int l = tid; l < 96 * 12; l += 256) {
        int h = l / 12, seg = l % 12;
        uint4 u = *(const uint4*)&attb[((size_t)(b * nP + h * nW + w)) * nS + seg * 8];
        *(uint4*)&As[h * 104 + seg * 8] = u;
    }
    const int lane = tid & 63, wave = tid >> 6;
    const int wr = wave & 1, wc = wave >> 1;
    const int lm = lane & 15, q = lane >> 4;
    int aoff[3], boff[4];
    #pragma unroll
    for (int i = 0; i < 3; ++i) aoff[i] = (wr * 48 + i * 16 + lm) * 104 + q * 8;
    #pragma unroll
    for (int j = 0; j < 4; ++j) boff[j] = (wc * 64 + j * 16 + lm) * 104 + q * 8;

    for (int ct = 0; ct < 4; ++ct) {
        if (ct) __syncthreads();       // prev epilogue done reading Ot
        for (int l = tid; l < 128 * 12; l += 256) {
            int cl = l / 12, seg = l % 12;
            uint4 u = *(const uint4*)&vH[((size_t)(b * nC + ct * 128 + cl)) * nP
                                         + w * nH + seg * 8];
            *(uint4*)&Bs[cl * 104 + seg * 8] = u;
        }
        __syncthreads();
        floatx4 acc[3][4];
        #pragma unroll
        for (int i = 0; i < 3; ++i)
            #pragma unroll
            for (int j = 0; j < 4; ++j) acc[i][j] = (floatx4){0.f, 0.f, 0.f, 0.f};
        #pragma unroll
        for (int ks = 0; ks < 3; ++ks) {
            short8 av[3], bvv[4];
            #pragma unroll
            for (int i = 0; i < 3; ++i) av[i] = *(const short8*)&As[aoff[i] + ks * 32];
            #pragma unroll
            for (int j = 0; j < 4; ++j) bvv[j] = *(const short8*)&Bs[boff[j] + ks * 32];
            #pragma unroll
            for (int i = 0; i < 3; ++i)
                #pragma unroll
                for (int j = 0; j < 4; ++j)
                    acc[i][j] = __builtin_amdgcn_mfma_f32_16x16x32_bf16(
                        av[i], bvv[j], acc[i][j], 0, 0, 0);
        }
        __syncthreads();               // all waves done reading Bs
        #pragma unroll
        for (int i = 0; i < 3; ++i) {
            #pragma unroll
            for (int r = 0; r < 4; ++r) {
                int h = wr * 48 + i * 16 + q * 4 + r;
                #pragma unroll
                for (int j = 0; j < 4; ++j)
                    Ot[h * 136 + wc * 64 + j * 16 + lm] = f2bf(acc[i][j][r]);
            }
        }
        __syncthreads();
        for (int l = tid; l < 96 * 16; l += 256) {
            int h = l >> 4, seg = l & 15;
            *(ushort8*)&oh[((size_t)(b * nP + h * nW + w)) * nC + ct * 128 + seg * 8] =
                *(const ushort8*)&Ot[h * 136 + seg * 8];
        }
    }
}

// ---------------------------------------------------------------------------
// aggW (MFMA) + epilogue: per (b,h): OW[w][c] = sum_u AW[w][u] * vW[c][u]
// Epilogue repack: s = gm*(acc+oh) -> LDS Ot fp32 [cl][w] (stride 100,
// overlays Bs+Os) -> vectorized float4 x-load / out-store
// (12 VMEM/thread/ct instead of 48 scalar).
// ---------------------------------------------------------------------------
__global__ __launch_bounds__(256) void aggW_kernel(
    const ushort* __restrict__ attb, const ushort* __restrict__ vW,
    const ushort* __restrict__ oh, const float* __restrict__ x,
    const float* __restrict__ gamma, float* __restrict__ out)
{
    __shared__ ushort As[96 * 104];                 // AW[w][u]
    __shared__ ushort BO[64 * 104 + 96 * 72];       // Bs | Os ; overlaid by Ot
    ushort* Bs = BO;
    ushort* Os = BO + 64 * 104;
    float*  Ot = (float*)BO;                        // [64][100] fp32 = 25.6KB
    const int b = blockIdx.y, h = blockIdx.x, tid = threadIdx.x;
    const float gm = gamma[0];

    for (int l = tid; l < 96 * 12; l += 256) {
        int ww = l / 12, seg = l % 12;
        uint4 u = *(const uint4*)&attb[((size_t)(b * nP + h * nW + ww)) * nS
                                       + 96 + seg * 8];
        *(uint4*)&As[ww * 104 + seg * 8] = u;
    }
    const int lane = tid & 63, wave = tid >> 6;
    const int wr = wave & 1, wc = wave >> 1;   // wr: w-half, wc: c-half
    const int lm = lane & 15, q = lane >> 4;
    int coff[2], woff[3];
    #pragma unroll
    for (int i = 0; i < 2; ++i) coff[i] = (wc * 32 + i * 16 + lm) * 104 + q * 8;
    #pragma unroll
    for (int j = 0; j < 3; ++j) woff[j] = (wr * 48 + j * 16 + lm) * 104 + q * 8;

    for (int ct = 0; ct < 8; ++ct) {
        if (ct) __syncthreads();       // prev epilogue done reading Ot
        for (int l = tid; l < 64 * 12; l += 256) {
            int cl = l / 12, seg = l % 12;
            uint4 u = *(const uint4*)&vW[((size_t)(b * nC + ct * 64 + cl)) * nP
                                         + h * nW + seg * 8];
            *(uint4*)&Bs[cl * 104 + seg * 8] = u;
        }
        for (int l = tid; l < 96 * 8; l += 256) {
            int ww = l / 8, seg = l % 8;
            uint4 u = *(const uint4*)&oh[((size_t)(b * nP + h * nW + ww)) * nC
                                         + ct * 64 + seg * 8];
            *(uint4*)&Os[ww * 72 + seg * 8] = u;
        }
        __syncthreads();
        floatx4 acc[2][3];
        #pragma unroll
        for (int i = 0; i < 2; ++i)
            #pragma unroll
            for (int j = 0; j < 3; ++j) acc[i][j] = (floatx4){0.f, 0.f, 0.f, 0.f};
        #pragma unroll
        for (int ks = 0; ks < 3; ++ks) {
            short8 cv[2], wv[3];
            #pragma unroll
            for (int i = 0; i < 2; ++i) cv[i] = *(const short8*)&Bs[coff[i] + ks * 32];
            #pragma unroll
            for (int j = 0; j < 3; ++j) wv[j] = *(const short8*)&As[woff[j] + ks * 32];
            #pragma unroll
            for (int i = 0; i < 2; ++i)
                #pragma unroll
                for (int j = 0; j < 3; ++j)
                    acc[i][j] = __builtin_amdgcn_mfma_f32_16x16x32_bf16(
                        cv[i], wv[j], acc[i][j], 0, 0, 0);
        }
        // fold oh while Os is still valid: s = gm*(acc + oh)
        float sv[2][3][4];
        #pragma unroll
        for (int i = 0; i < 2; ++i)
            #pragma unroll
            for (int r = 0; r < 4; ++r) {
                int cl = wc * 32 + i * 16 + q * 4 + r;
                #pragma unroll
                for (int j = 0; j < 3; ++j) {
                    int ww = wr * 48 + j * 16 + lm;
                    sv[i][j][r] = gm * (acc[i][j][r] + bf2f(Os[ww * 72 + cl]));
                }
            }
        __syncthreads();               // all waves done reading Bs/Os
        #pragma unroll
        for (int i = 0; i < 2; ++i)
            #pragma unroll
            for (int r = 0; r < 4; ++r) {
                int cl = wc * 32 + i * 16 + q * 4 + r;
                #pragma unroll
                for (int j = 0; j < 3; ++j)
                    Ot[cl * 100 + wr * 48 + j * 16 + lm] = sv[i][j][r];
            }
        __syncthreads();
        for (int l = tid; l < 64 * 24; l += 256) {
            int cl = l / 24, w4 = (l % 24) * 4;
            size_t gidx = ((size_t)(b * nC + ct * 64 + cl) * nH + h) * nW + w4;
            float4 xv = *(const float4*)&x[gidx];
            float4 s4 = *(const float4*)&Ot[cl * 100 + w4];
            float4 ov = make_float4(s4.x + xv.x, s4.y + xv.y,
                                    s4.z + xv.z, s4.w + xv.w);
            *(float4*)&out[gidx] = ov;
        }
    }
}

// ---------------------------------------------------------------------------
extern "C" void kernel_launch(void* const* d_in, const int* in_sizes, int n_in,
                              void* d_out, int out_size, void* d_ws, size_t ws_size,
                              hipStream_t stream)
{
    const float* x     = (const float*)d_in[0];
    const float* Wq    = (const float*)d_in[1];
    const float* bq    = (const float*)d_in[2];
    const float* Wk    = (const float*)d_in[3];
    const float* bk    = (const float*)d_in[4];
    const float* Wv    = (const float*)d_in[5];
    const float* bv    = (const float*)d_in[6];
    const float* gamma = (const float*)d_in[7];
    float* out = (float*)d_out;

    // Workspace layout (349.2 MB):
    //  R1 [nM*nC bf16 = 75.5MB]: xT until proj done, then vH (vtrans output)
    //  R2 [nM*128 f32 = 37.7MB]: qk
    //  R3 [nM*nC bf16 = 75.5MB]: vW
    //  R4 [nM*nS f32  = 56.6MB]: Wc+bc (bf16 weights) until scores, then att
    //  R5 [nM*nS bf16 = 28.3MB]: attb
    //  R6 [nM*nC bf16 = 75.5MB]: oh
    char* p = (char*)d_ws;
    ushort* xT  = (ushort*)p;
    ushort* vH  = (ushort*)p;
    p += (size_t)nM * nC * 2;
    float* qk   = (float*)p;
    p += (size_t)nM * 128 * 4;
    ushort* vW  = (ushort*)p;
    p += (size_t)nM * nC * 2;
    float* att  = (float*)p;
    ushort* Wc  = (ushort*)p;
    float* bc   = (float*)(p + (size_t)nO * nC * 2);
    p += (size_t)nM * nS * 4;
    ushort* attb = (ushort*)p;
    p += (size_t)nM * nS * 2;
    ushort* oh  = (ushort*)p;

    dim3 blk(256);
    transpose_kernel<<<dim3(nP / 64, nC / 64, nB), blk, 0, stream>>>(x, xT);
    wconv_kernel<<<dim3(nO), blk, 0, stream>>>(Wq, bq, Wk, bk, Wv, bv, Wc, bc);
    mfma_proj_kernel<<<dim3((nM / 128) * (nO / 128)), blk, 0, stream>>>(xT, Wc, bc, qk, vW);
    vtrans_kernel<<<dim3(nC, nB), blk, 0, stream>>>(vW, vH);
    score_kernel<<<dim3(nW, nB), blk, 0, stream>>>(qk, att, 0);
    score_kernel<<<dim3(nH, nB), blk, 0, stream>>>(qk, att, 1);
    softmax_kernel<<<dim3(nB * nP / 4), blk, 0, stream>>>(att, attb);
    aggH_kernel<<<dim3(nW, nB), blk, 0, stream>>>(attb, vH, oh);
    aggW_kernel<<<dim3(nH, nB), blk, 0, stream>>>(attb, vW, oh, x, gamma, out);
}